// Round 18
// baseline (200.162 us; speedup 1.0000x reference)
//
#include <hip/hip_runtime.h>

// GCN: 2x GCNConv (5->16->32) + global mean pool + linear head.
// v17: v15's proven scalar deep-batch gathers (8 feature lanes x 8 slots x
// depth 8 = 24 VMEM instrs/round -- v16's float4 variant halved wave-level
// memory parallelism and doubled gather16) + v16's epilogue fusions kept
// (lin1 fused into gather8, fin fused into gather16; agg buffers deleted)
// + zero-row tail masking. Build pipeline identical to v13/v15.

#define RANGE 256          // nodes per bucket (d>>8)
#define NB 391             // ceil(100000/256)
#define RPB (RANGE + 1)    // rowp entries per bucket (incl. end)
#define CAP 10240          // record capacity per bucket (exact fill ~8184+-90)
#define NBLK 512           // edge-pass blocks
#define CHUNKMAX 6400      // >= ceil(E/NBLK) = 6250
#define PSPREAD 8

// per-block LDS histogram of dst buckets -> blkcnt[blk][NB] (coalesced row)
__global__ void k_cnt(const int* __restrict__ dst, int E, int chunk,
                      int* __restrict__ blkcnt) {
    __shared__ int h[NB];
    for (int t = threadIdx.x; t < NB; t += blockDim.x) h[t] = 0;
    __syncthreads();
    int e0 = blockIdx.x * chunk;
    int e1 = min(e0 + chunk, E);
    for (int e = e0 + threadIdx.x; e < e1; e += blockDim.x)
        atomicAdd(&h[dst[e] >> 8], 1);
    __syncthreads();
    int* row = blkcnt + (size_t)blockIdx.x * NB;
    for (int t = threadIdx.x; t < NB; t += blockDim.x) row[t] = h[t];
}

// one block per bucket: exclusive scan over the NBLK per-block counts.
__global__ __launch_bounds__(512) void k_scanb(const int* __restrict__ blkcnt,
        int* __restrict__ base, int* __restrict__ bfill) {
    __shared__ int part[NBLK];
    int b = blockIdx.x, t = threadIdx.x;   // NBLK == 512 threads
    int v = blkcnt[(size_t)t * NB + b];    // column read, L2-cached
    part[t] = v;
    __syncthreads();
    for (int off = 1; off < NBLK; off <<= 1) {
        int u = (t >= off) ? part[t - off] : 0;
        __syncthreads();
        part[t] += u;
        __syncthreads();
    }
    base[(size_t)b * NBLK + t] = b * CAP + part[t] - v;  // coalesced row write
    if (t == NBLK - 1) bfill[b] = part[t];
}

// scatter records at exact offsets, via LDS staging sorted by bucket, then
// burst writes (consecutive lanes -> consecutive addresses per segment).
__global__ __launch_bounds__(512) void k_scat(const int* __restrict__ src,
        const int* __restrict__ dst, int E, int chunk,
        const int* __restrict__ base, unsigned int* __restrict__ recbuf) {
    __shared__ unsigned int lbuf[CHUNKMAX];
    __shared__ unsigned short bkt[CHUNKMAX];
    __shared__ int h[NB], lsc[NB], h2[NB], base_l[NB];
    __shared__ int sc[512];
    int t = threadIdx.x;
    if (t < NB) { h[t] = 0; h2[t] = 0; }
    __syncthreads();
    int e0 = blockIdx.x * chunk;
    int e1 = min(e0 + chunk, E);
    int len = e1 - e0;
    for (int e = e0 + t; e < e1; e += 512)
        atomicAdd(&h[__builtin_nontemporal_load(dst + e) >> 8], 1);
    __syncthreads();
    int v = (t < NB) ? h[t] : 0;
    sc[t] = v;
    __syncthreads();
    for (int off = 1; off < 512; off <<= 1) {
        int u = (t >= off) ? sc[t - off] : 0;
        __syncthreads();
        sc[t] += u;
        __syncthreads();
    }
    if (t < NB) {
        lsc[t] = sc[t] - v;
        base_l[t] = base[(size_t)t * NBLK + blockIdx.x];  // column read, L2-cached
    }
    __syncthreads();
    for (int e = e0 + t; e < e1; e += 512) {
        int d = __builtin_nontemporal_load(dst + e);
        int s = __builtin_nontemporal_load(src + e);
        int b = d >> 8;
        int r = atomicAdd(&h2[b], 1);
        int pos = lsc[b] + r;
        lbuf[pos] = ((unsigned)s << 8) | (unsigned)(d & 255);
        bkt[pos] = (unsigned short)b;
    }
    __syncthreads();
    for (int i = t; i < len; i += 512) {
        int b = bkt[i];
        recbuf[base_l[b] + (i - lsc[b])] = lbuf[i];  // burst per segment
    }
}

// per-bucket LDS counting sort by dst_local; cnt[] doubles as degree, so
// dinv and sx8 (= [dinv*x, 0,0,0]) are computed here too (fused prep).
__global__ __launch_bounds__(512) void k_sort(const int* __restrict__ bfill,
        const unsigned int* __restrict__ recbuf, int* __restrict__ rowp,
        int* __restrict__ srt, const float* __restrict__ x,
        float* __restrict__ dinv, float* __restrict__ sx8, int N) {
    __shared__ int cnt[RANGE], lbase[RANGE], rank[RANGE], sc[RANGE];
    int b = blockIdx.x;
    int t = threadIdx.x;
    if (t < RANGE) { cnt[t] = 0; rank[t] = 0; }
    __syncthreads();
    int len = bfill[b];
    int g0 = b * CAP;
    const unsigned* rb = recbuf + (size_t)g0;
    for (int r = t; r < len; r += 512)
        atomicAdd(&cnt[__builtin_nontemporal_load(rb + r) & 255], 1);
    __syncthreads();
    if (t < RANGE) sc[t] = cnt[t];
    __syncthreads();
    for (int off = 1; off < RANGE; off <<= 1) {
        int u = 0;
        if (t < RANGE && t >= off) u = sc[t - off];
        __syncthreads();
        if (t < RANGE) sc[t] += u;
        __syncthreads();
    }
    if (t < RANGE) {
        lbase[t] = sc[t] - cnt[t];
        rowp[b * RPB + t] = g0 + lbase[t];
        if (t == RANGE - 1) rowp[b * RPB + RANGE] = g0 + sc[t];
        int i = b * RANGE + t;
        if (i < N) {
            float di = rsqrtf((float)(cnt[t] + 1));
            dinv[i] = di;
            float4 a, bb;
            a.x = x[i * 5 + 0] * di; a.y = x[i * 5 + 1] * di;
            a.z = x[i * 5 + 2] * di; a.w = x[i * 5 + 3] * di;
            bb.x = x[i * 5 + 4] * di; bb.y = 0.f; bb.z = 0.f; bb.w = 0.f;
            float4* p = (float4*)(sx8 + (size_t)i * 8);
            p[0] = a; p[1] = bb;
        }
    }
    __syncthreads();
    for (int r = t; r < len; r += 512) {
        unsigned rec = __builtin_nontemporal_load(rb + r);
        int key = (int)(rec & 255);
        int pos = g0 + lbase[key] + atomicAdd(&rank[key], 1);
        srt[pos] = (int)(rec >> 8);   // plain store: L2-merged in bucket slice
    }
}

// one wave per node (+1 zero-row wave); 8 feature lanes x 8 slots x depth 8
// (64 edges per latency round, 24 VMEM instrs in flight). Tail slots clamp
// to zeroed row N. Epilogue: fused 5->16 linear -> writes g directly.
__global__ void k_gather8(const int* __restrict__ rowp, const int* __restrict__ srt,
                          const float* __restrict__ sx8, const float* __restrict__ W1,
                          const float* __restrict__ b1, const float* __restrict__ dinv,
                          float* __restrict__ g, int N) {
    __shared__ float sW[80], sb[16];
    if (threadIdx.x < 80) sW[threadIdx.x] = W1[threadIdx.x];
    if (threadIdx.x < 16) sb[threadIdx.x] = b1[threadIdx.x];
    __syncthreads();
    int wid = (blockIdx.x * blockDim.x + threadIdx.x) >> 6;
    int lane = threadIdx.x & 63;
    if (wid > N) return;
    if (wid == N) {               // zero row of g (for gather16 tails)
        if (lane < 16) g[(size_t)N * 16 + lane] = 0.f;
        return;
    }
    int k = lane & 7, j = lane >> 3;
    int b = wid >> 8, dl = wid & 255;
    int base = b * RPB + dl;
    int p0 = rowp[base], p1 = rowp[base + 1];
    float acc = 0.f;
    int p = p0 + j;
    while (p < p1) {
        int s0 = __builtin_nontemporal_load(srt + p);
        int s1 = __builtin_nontemporal_load(srt + p + 8);
        int s2 = __builtin_nontemporal_load(srt + p + 16);
        int s3 = __builtin_nontemporal_load(srt + p + 24);
        int s4 = __builtin_nontemporal_load(srt + p + 32);
        int s5 = __builtin_nontemporal_load(srt + p + 40);
        int s6 = __builtin_nontemporal_load(srt + p + 48);
        int s7 = __builtin_nontemporal_load(srt + p + 56);
        s1 = (p + 8  < p1) ? s1 : N;
        s2 = (p + 16 < p1) ? s2 : N;
        s3 = (p + 24 < p1) ? s3 : N;
        s4 = (p + 32 < p1) ? s4 : N;
        s5 = (p + 40 < p1) ? s5 : N;
        s6 = (p + 48 < p1) ? s6 : N;
        s7 = (p + 56 < p1) ? s7 : N;
        float v0 = sx8[(size_t)s0 * 8 + k];
        float v1 = sx8[(size_t)s1 * 8 + k];
        float v2 = sx8[(size_t)s2 * 8 + k];
        float v3 = sx8[(size_t)s3 * 8 + k];
        float v4 = sx8[(size_t)s4 * 8 + k];
        float v5 = sx8[(size_t)s5 * 8 + k];
        float v6 = sx8[(size_t)s6 * 8 + k];
        float v7 = sx8[(size_t)s7 * 8 + k];
        acc += ((v0 + v1) + (v2 + v3)) + ((v4 + v5) + (v6 + v7));
        p += 64;
    }
    acc += __shfl_xor(acc, 8, 64);
    acc += __shfl_xor(acc, 16, 64);
    acc += __shfl_xor(acc, 32, 64);
    acc += sx8[(size_t)wid * 8 + k];            // self-loop
    // lane d (d<5) holds aggregated feature d
    float a0 = __shfl(acc, 0, 64);
    float a1 = __shfl(acc, 1, 64);
    float a2 = __shfl(acc, 2, 64);
    float a3 = __shfl(acc, 3, 64);
    float a4 = __shfl(acc, 4, 64);
    if (lane < 16) {
        float di = dinv[wid];
        float h = a0 * sW[0 * 16 + lane];
        h = fmaf(a1, sW[1 * 16 + lane], h);
        h = fmaf(a2, sW[2 * 16 + lane], h);
        h = fmaf(a3, sW[3 * 16 + lane], h);
        h = fmaf(a4, sW[4 * 16 + lane], h);
        h = fmaxf(fmaf(di, h, sb[lane]), 0.f);
        g[(size_t)wid * 16 + lane] = h * di;
    }
}

// one wave per node; 8 feature lanes x 2 features (k, k+8 share the 64B
// g-row line) x 8 slots x depth 8. Epilogue: fused 16->32 linear + relu +
// fcW dot + per-wave pool atomic (was k_fin).
__global__ void k_gather16(const int* __restrict__ rowp, const int* __restrict__ srt,
                           const float* __restrict__ g, const float* __restrict__ W2,
                           const float* __restrict__ b2, const float* __restrict__ fcW,
                           const float* __restrict__ dinv, const int* __restrict__ batch,
                           float* __restrict__ pool, int* __restrict__ gcnt,
                           int N, int G) {
    __shared__ float sW[512], sb[32], sf[32];
    for (int t = threadIdx.x; t < 512; t += blockDim.x) sW[t] = W2[t];
    if (threadIdx.x < 32) {
        sb[threadIdx.x] = b2[threadIdx.x];
        sf[threadIdx.x] = fcW[threadIdx.x];
    }
    __syncthreads();
    int wid = (blockIdx.x * blockDim.x + threadIdx.x) >> 6;
    int lane = threadIdx.x & 63;
    if (wid >= N) return;
    int k = lane & 7, j = lane >> 3;
    int b = wid >> 8, dl = wid & 255;
    int base = b * RPB + dl;
    int p0 = rowp[base], p1 = rowp[base + 1];
    float acc0 = 0.f, acc1 = 0.f;
    int p = p0 + j;
    while (p < p1) {
        int s0 = __builtin_nontemporal_load(srt + p);
        int s1 = __builtin_nontemporal_load(srt + p + 8);
        int s2 = __builtin_nontemporal_load(srt + p + 16);
        int s3 = __builtin_nontemporal_load(srt + p + 24);
        int s4 = __builtin_nontemporal_load(srt + p + 32);
        int s5 = __builtin_nontemporal_load(srt + p + 40);
        int s6 = __builtin_nontemporal_load(srt + p + 48);
        int s7 = __builtin_nontemporal_load(srt + p + 56);
        s1 = (p + 8  < p1) ? s1 : N;
        s2 = (p + 16 < p1) ? s2 : N;
        s3 = (p + 24 < p1) ? s3 : N;
        s4 = (p + 32 < p1) ? s4 : N;
        s5 = (p + 40 < p1) ? s5 : N;
        s6 = (p + 48 < p1) ? s6 : N;
        s7 = (p + 56 < p1) ? s7 : N;
        float u0 = g[(size_t)s0 * 16 + k],     w0 = g[(size_t)s0 * 16 + k + 8];
        float u1 = g[(size_t)s1 * 16 + k],     w1 = g[(size_t)s1 * 16 + k + 8];
        float u2 = g[(size_t)s2 * 16 + k],     w2 = g[(size_t)s2 * 16 + k + 8];
        float u3 = g[(size_t)s3 * 16 + k],     w3 = g[(size_t)s3 * 16 + k + 8];
        float u4 = g[(size_t)s4 * 16 + k],     w4 = g[(size_t)s4 * 16 + k + 8];
        float u5 = g[(size_t)s5 * 16 + k],     w5 = g[(size_t)s5 * 16 + k + 8];
        float u6 = g[(size_t)s6 * 16 + k],     w6 = g[(size_t)s6 * 16 + k + 8];
        float u7 = g[(size_t)s7 * 16 + k],     w7 = g[(size_t)s7 * 16 + k + 8];
        acc0 += ((u0 + u1) + (u2 + u3)) + ((u4 + u5) + (u6 + u7));
        acc1 += ((w0 + w1) + (w2 + w3)) + ((w4 + w5) + (w6 + w7));
        p += 64;
    }
    acc0 += __shfl_xor(acc0, 8, 64);
    acc0 += __shfl_xor(acc0, 16, 64);
    acc0 += __shfl_xor(acc0, 32, 64);
    acc1 += __shfl_xor(acc1, 8, 64);
    acc1 += __shfl_xor(acc1, 16, 64);
    acc1 += __shfl_xor(acc1, 32, 64);
    acc0 += g[(size_t)wid * 16 + k];            // self-loop
    acc1 += g[(size_t)wid * 16 + k + 8];
    // lane d (d<8) holds features d (acc0) and d+8 (acc1)
    float a[16];
#pragma unroll
    for (int d = 0; d < 8; ++d) {
        a[d]     = __shfl(acc0, d, 64);
        a[8 + d] = __shfl(acc1, d, 64);
    }
    float di = dinv[wid];
    int jj = lane & 31;
    float h = 0.f;
#pragma unroll
    for (int kk = 0; kk < 16; ++kk) h = fmaf(a[kk], sW[kk * 32 + jj], h);
    h = fmaxf(fmaf(di, h, sb[jj]), 0.f);
    float c = (lane < 32) ? h * sf[jj] : 0.f;
#pragma unroll
    for (int off = 1; off <= 32; off <<= 1) c += __shfl_xor(c, off, 64);
    if (lane == 0) {
        int bidx = batch[wid];
        int slot = wid & (PSPREAD - 1);
        atomicAdd(&pool[slot * G + bidx], c);
        atomicAdd(&gcnt[slot * G + bidx], 1);
    }
}

__global__ void k_out(const float* __restrict__ pool, const int* __restrict__ gcnt,
                      const float* __restrict__ fcb, float* __restrict__ out, int G) {
    int gI = blockIdx.x * blockDim.x + threadIdx.x;
    if (gI >= G) return;
    float s = 0.f; int c = 0;
#pragma unroll
    for (int k = 0; k < PSPREAD; ++k) { s += pool[k * G + gI]; c += gcnt[k * G + gI]; }
    out[gI] = s / fmaxf((float)c, 1.f) + fcb[0];
}

extern "C" void kernel_launch(void* const* d_in, const int* in_sizes, int n_in,
                              void* d_out, int out_size, void* d_ws, size_t ws_size,
                              hipStream_t stream) {
    const float* x    = (const float*)d_in[0];
    const int*   ei   = (const int*)d_in[1];
    const int*   batch= (const int*)d_in[2];
    const float* W1   = (const float*)d_in[3];
    const float* b1   = (const float*)d_in[4];
    const float* W2   = (const float*)d_in[5];
    const float* b2   = (const float*)d_in[6];
    const float* fcW  = (const float*)d_in[7];
    const float* fcb  = (const float*)d_in[8];
    float* out = (float*)d_out;

    const int N = in_sizes[0] / 5;
    const int E = in_sizes[1] / 2;
    const int G = out_size;  // 1024
    const int chunk = (E + NBLK - 1) / NBLK;  // 6250 <= CHUNKMAX

    const int* src = ei;
    const int* dst = ei + E;

    // workspace carve, every buffer 256B-aligned
    char* ws = (char*)d_ws;
    size_t o = 0;
    auto carve = [&](size_t bytes) -> char* {
        char* p = ws + o;
        o += (bytes + 255) & ~(size_t)255;
        return p;
    };
    int*   bfill   = (int*)carve((size_t)4 * NB);
    int*   rowp    = (int*)carve((size_t)4 * (NB * RPB + 4));
    float* dinv    = (float*)carve((size_t)4 * N);
    float* sx8     = (float*)carve((size_t)32 * (N + 1));        // +1 zero row
    int*   srt     = (int*)carve((size_t)4 * NB * CAP + 256);    // 16 MB + pad
    char*  rbase   = carve((size_t)4 * NB * CAP);                // 16 MB
    // blkcnt/base alias srt (dead before k_sort writes srt)
    int*   blkcnt  = srt;                                        // [NBLK][NB]
    int*   base    = srt + (size_t)NBLK * NB;                    // [NB][NBLK]
    unsigned int* recbuf = (unsigned int*)rbase;                 // dead after k_sort
    float* g       = (float*)rbase;                              // (N+1)x16 floats, written post-k_sort
    float* pool    = (float*)carve((size_t)4 * PSPREAD * G);
    int*   gcnt    = (int*)carve((size_t)4 * PSPREAD * G);

    hipMemsetAsync(pool, 0, (size_t)4 * PSPREAD * G, stream);
    hipMemsetAsync(gcnt, 0, (size_t)4 * PSPREAD * G, stream);
    hipMemsetAsync(sx8 + (size_t)8 * N, 0, 32, stream);          // zero row N

    k_cnt<<<NBLK, 256, 0, stream>>>(dst, E, chunk, blkcnt);
    k_scanb<<<NB, 512, 0, stream>>>(blkcnt, base, bfill);
    k_scat<<<NBLK, 512, 0, stream>>>(src, dst, E, chunk, base, recbuf);
    k_sort<<<NB, 512, 0, stream>>>(bfill, recbuf, rowp, srt, x, dinv, sx8, N);
    {
        long long T = (long long)(N + 1) * 64;
        k_gather8<<<(int)((T + 255) / 256), 256, 0, stream>>>(rowp, srt, sx8, W1, b1, dinv, g, N);
    }
    {
        long long T = (long long)N * 64;
        k_gather16<<<(int)((T + 255) / 256), 256, 0, stream>>>(rowp, srt, g, W2, b2, fcW,
                                                              dinv, batch, pool, gcnt, N, G);
    }
    k_out<<<(G + 255) / 256, 256, 0, stream>>>(pool, gcnt, fcb, out, G);
}

// Round 19
// 171.460 us; speedup vs baseline: 1.1674x; 1.1674x over previous
//
#include <hip/hip_runtime.h>
#include <hip/hip_fp16.h>

// GCN: 2x GCNConv (5->16->32) + global mean pool + linear head.
// v18: exact v15 structure (fusions of v16/v17 reverted -- both measured
// gather16 at 83us vs v15's 44us regardless of load shape; the fused-epilogue
// kernels lose ~2x on the fetch path). One change vs v15: the g table is
// stored as fp16 (3.2 MB instead of 6.4 MB -> per-XCD-L2-resident, same
// property that keeps gather8's table at 26 MB FETCH). Error budget ~1e-4
// vs 4.6e-4 threshold.

#define RANGE 256          // nodes per bucket (d>>8)
#define NB 391             // ceil(100000/256)
#define RPB (RANGE + 1)    // rowp entries per bucket (incl. end)
#define CAP 10240          // record capacity per bucket (exact fill ~8184+-90)
#define NBLK 512           // edge-pass blocks
#define CHUNKMAX 6400      // >= ceil(E/NBLK) = 6250
#define PSPREAD 8

// per-block LDS histogram of dst buckets -> blkcnt[blk][NB] (coalesced row)
__global__ void k_cnt(const int* __restrict__ dst, int E, int chunk,
                      int* __restrict__ blkcnt) {
    __shared__ int h[NB];
    for (int t = threadIdx.x; t < NB; t += blockDim.x) h[t] = 0;
    __syncthreads();
    int e0 = blockIdx.x * chunk;
    int e1 = min(e0 + chunk, E);
    for (int e = e0 + threadIdx.x; e < e1; e += blockDim.x)
        atomicAdd(&h[dst[e] >> 8], 1);
    __syncthreads();
    int* row = blkcnt + (size_t)blockIdx.x * NB;
    for (int t = threadIdx.x; t < NB; t += blockDim.x) row[t] = h[t];
}

// one block per bucket: exclusive scan over the NBLK per-block counts.
__global__ __launch_bounds__(512) void k_scanb(const int* __restrict__ blkcnt,
        int* __restrict__ base, int* __restrict__ bfill) {
    __shared__ int part[NBLK];
    int b = blockIdx.x, t = threadIdx.x;   // NBLK == 512 threads
    int v = blkcnt[(size_t)t * NB + b];    // column read, L2-cached
    part[t] = v;
    __syncthreads();
    for (int off = 1; off < NBLK; off <<= 1) {
        int u = (t >= off) ? part[t - off] : 0;
        __syncthreads();
        part[t] += u;
        __syncthreads();
    }
    base[(size_t)b * NBLK + t] = b * CAP + part[t] - v;  // coalesced row write
    if (t == NBLK - 1) bfill[b] = part[t];
}

// scatter records at exact offsets, via LDS staging sorted by bucket, then
// burst writes (consecutive lanes -> consecutive addresses per segment).
__global__ __launch_bounds__(512) void k_scat(const int* __restrict__ src,
        const int* __restrict__ dst, int E, int chunk,
        const int* __restrict__ base, unsigned int* __restrict__ recbuf) {
    __shared__ unsigned int lbuf[CHUNKMAX];
    __shared__ unsigned short bkt[CHUNKMAX];
    __shared__ int h[NB], lsc[NB], h2[NB], base_l[NB];
    __shared__ int sc[512];
    int t = threadIdx.x;
    if (t < NB) { h[t] = 0; h2[t] = 0; }
    __syncthreads();
    int e0 = blockIdx.x * chunk;
    int e1 = min(e0 + chunk, E);
    int len = e1 - e0;
    for (int e = e0 + t; e < e1; e += 512)
        atomicAdd(&h[__builtin_nontemporal_load(dst + e) >> 8], 1);
    __syncthreads();
    int v = (t < NB) ? h[t] : 0;
    sc[t] = v;
    __syncthreads();
    for (int off = 1; off < 512; off <<= 1) {
        int u = (t >= off) ? sc[t - off] : 0;
        __syncthreads();
        sc[t] += u;
        __syncthreads();
    }
    if (t < NB) {
        lsc[t] = sc[t] - v;
        base_l[t] = base[(size_t)t * NBLK + blockIdx.x];  // column read, L2-cached
    }
    __syncthreads();
    for (int e = e0 + t; e < e1; e += 512) {
        int d = __builtin_nontemporal_load(dst + e);
        int s = __builtin_nontemporal_load(src + e);
        int b = d >> 8;
        int r = atomicAdd(&h2[b], 1);
        int pos = lsc[b] + r;
        lbuf[pos] = ((unsigned)s << 8) | (unsigned)(d & 255);
        bkt[pos] = (unsigned short)b;
    }
    __syncthreads();
    for (int i = t; i < len; i += 512) {
        int b = bkt[i];
        recbuf[base_l[b] + (i - lsc[b])] = lbuf[i];  // burst per segment
    }
}

// per-bucket LDS counting sort by dst_local; cnt[] doubles as degree, so
// dinv and sx8 (= [dinv*x, 0,0,0]) are computed here too (fused prep).
__global__ __launch_bounds__(512) void k_sort(const int* __restrict__ bfill,
        const unsigned int* __restrict__ recbuf, int* __restrict__ rowp,
        int* __restrict__ srt, const float* __restrict__ x,
        float* __restrict__ dinv, float* __restrict__ sx8, int N) {
    __shared__ int cnt[RANGE], lbase[RANGE], rank[RANGE], sc[RANGE];
    int b = blockIdx.x;
    int t = threadIdx.x;
    if (t < RANGE) { cnt[t] = 0; rank[t] = 0; }
    __syncthreads();
    int len = bfill[b];
    int g0 = b * CAP;
    const unsigned* rb = recbuf + (size_t)g0;
    for (int r = t; r < len; r += 512)
        atomicAdd(&cnt[__builtin_nontemporal_load(rb + r) & 255], 1);
    __syncthreads();
    if (t < RANGE) sc[t] = cnt[t];
    __syncthreads();
    for (int off = 1; off < RANGE; off <<= 1) {
        int u = 0;
        if (t < RANGE && t >= off) u = sc[t - off];
        __syncthreads();
        if (t < RANGE) sc[t] += u;
        __syncthreads();
    }
    if (t < RANGE) {
        lbase[t] = sc[t] - cnt[t];
        rowp[b * RPB + t] = g0 + lbase[t];
        if (t == RANGE - 1) rowp[b * RPB + RANGE] = g0 + sc[t];
        int i = b * RANGE + t;
        if (i < N) {
            float di = rsqrtf((float)(cnt[t] + 1));
            dinv[i] = di;
            float4 a, bb;
            a.x = x[i * 5 + 0] * di; a.y = x[i * 5 + 1] * di;
            a.z = x[i * 5 + 2] * di; a.w = x[i * 5 + 3] * di;
            bb.x = x[i * 5 + 4] * di; bb.y = 0.f; bb.z = 0.f; bb.w = 0.f;
            float4* p = (float4*)(sx8 + (size_t)i * 8);
            p[0] = a; p[1] = bb;
        }
    }
    __syncthreads();
    for (int r = t; r < len; r += 512) {
        unsigned rec = __builtin_nontemporal_load(rb + r);
        int key = (int)(rec & 255);
        int pos = g0 + lbase[key] + atomicAdd(&rank[key], 1);
        srt[pos] = (int)(rec >> 8);   // plain store: L2-merged in bucket slice
    }
}

// one wave per node; 8 feature lanes x 8 row slots; 8-deep batched loads:
// one latency round-trip covers deg <= 64. srt is padded; clamped indices.
__global__ void k_gather8(const int* __restrict__ rowp, const int* __restrict__ srt,
                          const float* __restrict__ sx8, float* __restrict__ agg8, int N) {
    int wid = (blockIdx.x * blockDim.x + threadIdx.x) >> 6;
    int lane = threadIdx.x & 63;
    if (wid >= N) return;
    int k = lane & 7, j = lane >> 3;
    int b = wid >> 8, dl = wid & 255;
    int base = b * RPB + dl;
    int p0 = rowp[base], p1 = rowp[base + 1];
    float acc = 0.f;
    int p = p0 + j;
    while (p < p1) {
        int s0 = __builtin_nontemporal_load(srt + p);
        int s1 = __builtin_nontemporal_load(srt + p + 8);
        int s2 = __builtin_nontemporal_load(srt + p + 16);
        int s3 = __builtin_nontemporal_load(srt + p + 24);
        int s4 = __builtin_nontemporal_load(srt + p + 32);
        int s5 = __builtin_nontemporal_load(srt + p + 40);
        int s6 = __builtin_nontemporal_load(srt + p + 48);
        int s7 = __builtin_nontemporal_load(srt + p + 56);
        s1 = (p + 8  < p1) ? s1 : 0;
        s2 = (p + 16 < p1) ? s2 : 0;
        s3 = (p + 24 < p1) ? s3 : 0;
        s4 = (p + 32 < p1) ? s4 : 0;
        s5 = (p + 40 < p1) ? s5 : 0;
        s6 = (p + 48 < p1) ? s6 : 0;
        s7 = (p + 56 < p1) ? s7 : 0;
        float v0 = sx8[(size_t)s0 * 8 + k];
        float v1 = sx8[(size_t)s1 * 8 + k];
        float v2 = sx8[(size_t)s2 * 8 + k];
        float v3 = sx8[(size_t)s3 * 8 + k];
        float v4 = sx8[(size_t)s4 * 8 + k];
        float v5 = sx8[(size_t)s5 * 8 + k];
        float v6 = sx8[(size_t)s6 * 8 + k];
        float v7 = sx8[(size_t)s7 * 8 + k];
        acc += v0;
        acc += (p + 8  < p1) ? v1 : 0.f;
        acc += (p + 16 < p1) ? v2 : 0.f;
        acc += (p + 24 < p1) ? v3 : 0.f;
        acc += (p + 32 < p1) ? v4 : 0.f;
        acc += (p + 40 < p1) ? v5 : 0.f;
        acc += (p + 48 < p1) ? v6 : 0.f;
        acc += (p + 56 < p1) ? v7 : 0.f;
        p += 64;
    }
    acc += __shfl_xor(acc, 8, 64);
    acc += __shfl_xor(acc, 16, 64);
    acc += __shfl_xor(acc, 32, 64);
    if (lane < 8) agg8[(size_t)wid * 8 + k] = acc + sx8[(size_t)wid * 8 + k];
}

// h1 = relu(dinv*(agg8[:5]@W1) + b1); g = dinv*h1 (16), stored fp16
__global__ void k_lin1(const float* __restrict__ agg8, const float* __restrict__ dinv,
                       const float* __restrict__ W1, const float* __restrict__ b1,
                       __half* __restrict__ g, int N) {
    __shared__ float sW[80], sb[16];
    if (threadIdx.x < 80) sW[threadIdx.x] = W1[threadIdx.x];
    if (threadIdx.x < 16) sb[threadIdx.x] = b1[threadIdx.x];
    __syncthreads();
    int i = blockIdx.x * blockDim.x + threadIdx.x;
    if (i >= N) return;
    float di = dinv[i];
    const float4* a4 = (const float4*)(agg8 + (size_t)i * 8);
    float4 v0 = a4[0], v1 = a4[1];
    float a[5] = {v0.x, v0.y, v0.z, v0.w, v1.x};
    union { __half h[16]; uint4 u[2]; } pk;
#pragma unroll
    for (int kk = 0; kk < 16; ++kk) {
        float h = 0.f;
#pragma unroll
        for (int d = 0; d < 5; ++d) h = fmaf(a[d], sW[d * 16 + kk], h);
        h = fmaxf(fmaf(di, h, sb[kk]), 0.f);
        pk.h[kk] = __float2half(h * di);
    }
    uint4* gp = (uint4*)(g + (size_t)i * 16);   // 32B row
    gp[0] = pk.u[0];
    gp[1] = pk.u[1];
}

// one wave per node; 8 feature lanes x 2 features (k, k+8 share the 32B
// fp16 g-row) x 8 slots x depth 8. Table is 3.2 MB -> per-XCD-L2-resident.
__global__ void k_gather16(const int* __restrict__ rowp, const int* __restrict__ srt,
                           const __half* __restrict__ g, float* __restrict__ agg16, int N) {
    int wid = (blockIdx.x * blockDim.x + threadIdx.x) >> 6;
    int lane = threadIdx.x & 63;
    if (wid >= N) return;
    int k = lane & 7, j = lane >> 3;
    int b = wid >> 8, dl = wid & 255;
    int base = b * RPB + dl;
    int p0 = rowp[base], p1 = rowp[base + 1];
    float acc0 = 0.f, acc1 = 0.f;
    int p = p0 + j;
    while (p < p1) {
        int s0 = __builtin_nontemporal_load(srt + p);
        int s1 = __builtin_nontemporal_load(srt + p + 8);
        int s2 = __builtin_nontemporal_load(srt + p + 16);
        int s3 = __builtin_nontemporal_load(srt + p + 24);
        int s4 = __builtin_nontemporal_load(srt + p + 32);
        int s5 = __builtin_nontemporal_load(srt + p + 40);
        int s6 = __builtin_nontemporal_load(srt + p + 48);
        int s7 = __builtin_nontemporal_load(srt + p + 56);
        s1 = (p + 8  < p1) ? s1 : 0;
        s2 = (p + 16 < p1) ? s2 : 0;
        s3 = (p + 24 < p1) ? s3 : 0;
        s4 = (p + 32 < p1) ? s4 : 0;
        s5 = (p + 40 < p1) ? s5 : 0;
        s6 = (p + 48 < p1) ? s6 : 0;
        s7 = (p + 56 < p1) ? s7 : 0;
        float u0 = __half2float(g[(size_t)s0 * 16 + k]), w0 = __half2float(g[(size_t)s0 * 16 + k + 8]);
        float u1 = __half2float(g[(size_t)s1 * 16 + k]), w1 = __half2float(g[(size_t)s1 * 16 + k + 8]);
        float u2 = __half2float(g[(size_t)s2 * 16 + k]), w2 = __half2float(g[(size_t)s2 * 16 + k + 8]);
        float u3 = __half2float(g[(size_t)s3 * 16 + k]), w3 = __half2float(g[(size_t)s3 * 16 + k + 8]);
        float u4 = __half2float(g[(size_t)s4 * 16 + k]), w4 = __half2float(g[(size_t)s4 * 16 + k + 8]);
        float u5 = __half2float(g[(size_t)s5 * 16 + k]), w5 = __half2float(g[(size_t)s5 * 16 + k + 8]);
        float u6 = __half2float(g[(size_t)s6 * 16 + k]), w6 = __half2float(g[(size_t)s6 * 16 + k + 8]);
        float u7 = __half2float(g[(size_t)s7 * 16 + k]), w7 = __half2float(g[(size_t)s7 * 16 + k + 8]);
        acc0 += u0;                       acc1 += w0;
        acc0 += (p + 8  < p1) ? u1 : 0.f; acc1 += (p + 8  < p1) ? w1 : 0.f;
        acc0 += (p + 16 < p1) ? u2 : 0.f; acc1 += (p + 16 < p1) ? w2 : 0.f;
        acc0 += (p + 24 < p1) ? u3 : 0.f; acc1 += (p + 24 < p1) ? w3 : 0.f;
        acc0 += (p + 32 < p1) ? u4 : 0.f; acc1 += (p + 32 < p1) ? w4 : 0.f;
        acc0 += (p + 40 < p1) ? u5 : 0.f; acc1 += (p + 40 < p1) ? w5 : 0.f;
        acc0 += (p + 48 < p1) ? u6 : 0.f; acc1 += (p + 48 < p1) ? w6 : 0.f;
        acc0 += (p + 56 < p1) ? u7 : 0.f; acc1 += (p + 56 < p1) ? w7 : 0.f;
        p += 64;
    }
    acc0 += __shfl_xor(acc0, 8, 64);
    acc0 += __shfl_xor(acc0, 16, 64);
    acc0 += __shfl_xor(acc0, 32, 64);
    acc1 += __shfl_xor(acc1, 8, 64);
    acc1 += __shfl_xor(acc1, 16, 64);
    acc1 += __shfl_xor(acc1, 32, 64);
    if (lane < 8) {
        agg16[(size_t)wid * 16 + k]     = acc0 + __half2float(g[(size_t)wid * 16 + k]);
        agg16[(size_t)wid * 16 + k + 8] = acc1 + __half2float(g[(size_t)wid * 16 + k + 8]);
    }
}

// h2 = relu(dinv*(agg16@W2) + b2); c = h2 . fcW; spread-8 pool atomics
__global__ void k_fin(const float* __restrict__ agg16, const float* __restrict__ dinv,
                      const float* __restrict__ W2, const float* __restrict__ b2,
                      const float* __restrict__ fcW, const int* __restrict__ batch,
                      float* __restrict__ pool, int* __restrict__ gcnt, int N, int G) {
    __shared__ float sW[512], sb[32], sf[32];
    for (int t = threadIdx.x; t < 512; t += blockDim.x) sW[t] = W2[t];
    if (threadIdx.x < 32) {
        sb[threadIdx.x] = b2[threadIdx.x];
        sf[threadIdx.x] = fcW[threadIdx.x];
    }
    __syncthreads();
    int i = blockIdx.x * blockDim.x + threadIdx.x;
    if (i >= N) return;
    float di = dinv[i];
    float a[16];
    const float4* a4 = (const float4*)(agg16 + (size_t)i * 16);
#pragma unroll
    for (int q = 0; q < 4; ++q) {
        float4 v = a4[q];
        a[q * 4 + 0] = v.x; a[q * 4 + 1] = v.y; a[q * 4 + 2] = v.z; a[q * 4 + 3] = v.w;
    }
    float c = 0.f;
#pragma unroll
    for (int jj = 0; jj < 32; ++jj) {
        float acc2 = 0.f;
#pragma unroll
        for (int kk = 0; kk < 16; ++kk) acc2 = fmaf(a[kk], sW[kk * 32 + jj], acc2);
        float h = fmaxf(fmaf(di, acc2, sb[jj]), 0.f);
        c = fmaf(h, sf[jj], c);
    }
    int bidx = batch[i];
    int slot = i & (PSPREAD - 1);
    atomicAdd(&pool[slot * G + bidx], c);
    atomicAdd(&gcnt[slot * G + bidx], 1);
}

__global__ void k_out(const float* __restrict__ pool, const int* __restrict__ gcnt,
                      const float* __restrict__ fcb, float* __restrict__ out, int G) {
    int gI = blockIdx.x * blockDim.x + threadIdx.x;
    if (gI >= G) return;
    float s = 0.f; int c = 0;
#pragma unroll
    for (int k = 0; k < PSPREAD; ++k) { s += pool[k * G + gI]; c += gcnt[k * G + gI]; }
    out[gI] = s / fmaxf((float)c, 1.f) + fcb[0];
}

extern "C" void kernel_launch(void* const* d_in, const int* in_sizes, int n_in,
                              void* d_out, int out_size, void* d_ws, size_t ws_size,
                              hipStream_t stream) {
    const float* x    = (const float*)d_in[0];
    const int*   ei   = (const int*)d_in[1];
    const int*   batch= (const int*)d_in[2];
    const float* W1   = (const float*)d_in[3];
    const float* b1   = (const float*)d_in[4];
    const float* W2   = (const float*)d_in[5];
    const float* b2   = (const float*)d_in[6];
    const float* fcW  = (const float*)d_in[7];
    const float* fcb  = (const float*)d_in[8];
    float* out = (float*)d_out;

    const int N = in_sizes[0] / 5;
    const int E = in_sizes[1] / 2;
    const int G = out_size;  // 1024
    const int chunk = (E + NBLK - 1) / NBLK;  // 6250 <= CHUNKMAX

    const int* src = ei;
    const int* dst = ei + E;

    // workspace carve, every buffer 256B-aligned
    char* ws = (char*)d_ws;
    size_t o = 0;
    auto carve = [&](size_t bytes) -> char* {
        char* p = ws + o;
        o += (bytes + 255) & ~(size_t)255;
        return p;
    };
    int*   bfill   = (int*)carve((size_t)4 * NB);
    int*   rowp    = (int*)carve((size_t)4 * (NB * RPB + 4));
    float* dinv    = (float*)carve((size_t)4 * N);
    float* sx8     = (float*)carve((size_t)32 * N);              // 3.2 MB (written inside k_sort)
    float* agg8    = (float*)carve((size_t)32 * N);              // 3.2 MB
    int*   srt     = (int*)carve((size_t)4 * NB * CAP + 256);    // 16 MB + pad
    char*  rbase   = carve((size_t)4 * NB * CAP);                // 16 MB
    // blkcnt/base alias srt (dead before k_sort writes srt)
    int*   blkcnt  = srt;                                        // [NBLK][NB]
    int*   base    = srt + (size_t)NBLK * NB;                    // [NB][NBLK]
    unsigned int* recbuf = (unsigned int*)rbase;                 // dead after k_sort
    __half* g      = (__half*)rbase;                             // N x 16 halves (3.2 MB), post-k_sort
    float* agg16   = (float*)(rbase + (size_t)32 * N);           // N x 16 floats (6.4 MB), post-k_sort
    float* pool    = (float*)carve((size_t)4 * PSPREAD * G);
    int*   gcnt    = (int*)carve((size_t)4 * PSPREAD * G);

    hipMemsetAsync(pool, 0, (size_t)4 * PSPREAD * G, stream);
    hipMemsetAsync(gcnt, 0, (size_t)4 * PSPREAD * G, stream);

    k_cnt<<<NBLK, 256, 0, stream>>>(dst, E, chunk, blkcnt);
    k_scanb<<<NB, 512, 0, stream>>>(blkcnt, base, bfill);
    k_scat<<<NBLK, 512, 0, stream>>>(src, dst, E, chunk, base, recbuf);
    k_sort<<<NB, 512, 0, stream>>>(bfill, recbuf, rowp, srt, x, dinv, sx8, N);
    {
        int blocks = (int)(((long long)N * 64 + 255) / 256);
        k_gather8<<<blocks, 256, 0, stream>>>(rowp, srt, sx8, agg8, N);
    }
    k_lin1<<<(N + 255) / 256, 256, 0, stream>>>(agg8, dinv, W1, b1, g, N);
    {
        int blocks = (int)(((long long)N * 64 + 255) / 256);
        k_gather16<<<blocks, 256, 0, stream>>>(rowp, srt, g, agg16, N);
    }
    k_fin<<<(N + 255) / 256, 256, 0, stream>>>(agg16, dinv, W2, b2, fcW, batch, pool, gcnt, N, G);
    k_out<<<(G + 255) / 256, 256, 0, stream>>>(pool, gcnt, fcb, out, G);
}

// Round 20
// 166.803 us; speedup vs baseline: 1.2000x; 1.0279x over previous
//
#include <hip/hip_runtime.h>
#include <hip/hip_fp16.h>

// GCN: 2x GCNConv (5->16->32) + global mean pool + linear head.
// v19: v18 (fp16 g table, L2-resident: FETCH 96->23.5MB) + instruction-count
// cuts in the now-VALU-bound gather16: packed __half2 loads (one 4B load per
// slot covers a feature pair -> 8 g-loads/round instead of 16 scalar) and
// zero-row-at-N tail clamping (unconditional accumulate, no cndmask-adds).
// Build pipeline byte-identical to v13/v15/v18.

#define RANGE 256          // nodes per bucket (d>>8)
#define NB 391             // ceil(100000/256)
#define RPB (RANGE + 1)    // rowp entries per bucket (incl. end)
#define CAP 10240          // record capacity per bucket (exact fill ~8184+-90)
#define NBLK 512           // edge-pass blocks
#define CHUNKMAX 6400      // >= ceil(E/NBLK) = 6250
#define PSPREAD 8

// per-block LDS histogram of dst buckets -> blkcnt[blk][NB] (coalesced row)
__global__ void k_cnt(const int* __restrict__ dst, int E, int chunk,
                      int* __restrict__ blkcnt) {
    __shared__ int h[NB];
    for (int t = threadIdx.x; t < NB; t += blockDim.x) h[t] = 0;
    __syncthreads();
    int e0 = blockIdx.x * chunk;
    int e1 = min(e0 + chunk, E);
    for (int e = e0 + threadIdx.x; e < e1; e += blockDim.x)
        atomicAdd(&h[dst[e] >> 8], 1);
    __syncthreads();
    int* row = blkcnt + (size_t)blockIdx.x * NB;
    for (int t = threadIdx.x; t < NB; t += blockDim.x) row[t] = h[t];
}

// one block per bucket: exclusive scan over the NBLK per-block counts.
__global__ __launch_bounds__(512) void k_scanb(const int* __restrict__ blkcnt,
        int* __restrict__ base, int* __restrict__ bfill) {
    __shared__ int part[NBLK];
    int b = blockIdx.x, t = threadIdx.x;   // NBLK == 512 threads
    int v = blkcnt[(size_t)t * NB + b];    // column read, L2-cached
    part[t] = v;
    __syncthreads();
    for (int off = 1; off < NBLK; off <<= 1) {
        int u = (t >= off) ? part[t - off] : 0;
        __syncthreads();
        part[t] += u;
        __syncthreads();
    }
    base[(size_t)b * NBLK + t] = b * CAP + part[t] - v;  // coalesced row write
    if (t == NBLK - 1) bfill[b] = part[t];
}

// scatter records at exact offsets, via LDS staging sorted by bucket, then
// burst writes (consecutive lanes -> consecutive addresses per segment).
__global__ __launch_bounds__(512) void k_scat(const int* __restrict__ src,
        const int* __restrict__ dst, int E, int chunk,
        const int* __restrict__ base, unsigned int* __restrict__ recbuf) {
    __shared__ unsigned int lbuf[CHUNKMAX];
    __shared__ unsigned short bkt[CHUNKMAX];
    __shared__ int h[NB], lsc[NB], h2[NB], base_l[NB];
    __shared__ int sc[512];
    int t = threadIdx.x;
    if (t < NB) { h[t] = 0; h2[t] = 0; }
    __syncthreads();
    int e0 = blockIdx.x * chunk;
    int e1 = min(e0 + chunk, E);
    int len = e1 - e0;
    for (int e = e0 + t; e < e1; e += 512)
        atomicAdd(&h[__builtin_nontemporal_load(dst + e) >> 8], 1);
    __syncthreads();
    int v = (t < NB) ? h[t] : 0;
    sc[t] = v;
    __syncthreads();
    for (int off = 1; off < 512; off <<= 1) {
        int u = (t >= off) ? sc[t - off] : 0;
        __syncthreads();
        sc[t] += u;
        __syncthreads();
    }
    if (t < NB) {
        lsc[t] = sc[t] - v;
        base_l[t] = base[(size_t)t * NBLK + blockIdx.x];  // column read, L2-cached
    }
    __syncthreads();
    for (int e = e0 + t; e < e1; e += 512) {
        int d = __builtin_nontemporal_load(dst + e);
        int s = __builtin_nontemporal_load(src + e);
        int b = d >> 8;
        int r = atomicAdd(&h2[b], 1);
        int pos = lsc[b] + r;
        lbuf[pos] = ((unsigned)s << 8) | (unsigned)(d & 255);
        bkt[pos] = (unsigned short)b;
    }
    __syncthreads();
    for (int i = t; i < len; i += 512) {
        int b = bkt[i];
        recbuf[base_l[b] + (i - lsc[b])] = lbuf[i];  // burst per segment
    }
}

// per-bucket LDS counting sort by dst_local; cnt[] doubles as degree, so
// dinv and sx8 (= [dinv*x, 0,0,0]) are computed here too (fused prep).
__global__ __launch_bounds__(512) void k_sort(const int* __restrict__ bfill,
        const unsigned int* __restrict__ recbuf, int* __restrict__ rowp,
        int* __restrict__ srt, const float* __restrict__ x,
        float* __restrict__ dinv, float* __restrict__ sx8, int N) {
    __shared__ int cnt[RANGE], lbase[RANGE], rank[RANGE], sc[RANGE];
    int b = blockIdx.x;
    int t = threadIdx.x;
    if (t < RANGE) { cnt[t] = 0; rank[t] = 0; }
    __syncthreads();
    int len = bfill[b];
    int g0 = b * CAP;
    const unsigned* rb = recbuf + (size_t)g0;
    for (int r = t; r < len; r += 512)
        atomicAdd(&cnt[__builtin_nontemporal_load(rb + r) & 255], 1);
    __syncthreads();
    if (t < RANGE) sc[t] = cnt[t];
    __syncthreads();
    for (int off = 1; off < RANGE; off <<= 1) {
        int u = 0;
        if (t < RANGE && t >= off) u = sc[t - off];
        __syncthreads();
        if (t < RANGE) sc[t] += u;
        __syncthreads();
    }
    if (t < RANGE) {
        lbase[t] = sc[t] - cnt[t];
        rowp[b * RPB + t] = g0 + lbase[t];
        if (t == RANGE - 1) rowp[b * RPB + RANGE] = g0 + sc[t];
        int i = b * RANGE + t;
        if (i < N) {
            float di = rsqrtf((float)(cnt[t] + 1));
            dinv[i] = di;
            float4 a, bb;
            a.x = x[i * 5 + 0] * di; a.y = x[i * 5 + 1] * di;
            a.z = x[i * 5 + 2] * di; a.w = x[i * 5 + 3] * di;
            bb.x = x[i * 5 + 4] * di; bb.y = 0.f; bb.z = 0.f; bb.w = 0.f;
            float4* p = (float4*)(sx8 + (size_t)i * 8);
            p[0] = a; p[1] = bb;
        }
    }
    __syncthreads();
    for (int r = t; r < len; r += 512) {
        unsigned rec = __builtin_nontemporal_load(rb + r);
        int key = (int)(rec & 255);
        int pos = g0 + lbase[key] + atomicAdd(&rank[key], 1);
        srt[pos] = (int)(rec >> 8);   // plain store: L2-merged in bucket slice
    }
}

// one wave per node; 8 feature lanes x 8 row slots; 8-deep batched loads,
// tail slots clamp to the zeroed row N -> unconditional accumulate.
__global__ void k_gather8(const int* __restrict__ rowp, const int* __restrict__ srt,
                          const float* __restrict__ sx8, float* __restrict__ agg8, int N) {
    int wid = (blockIdx.x * blockDim.x + threadIdx.x) >> 6;
    int lane = threadIdx.x & 63;
    if (wid >= N) return;
    int k = lane & 7, j = lane >> 3;
    int b = wid >> 8, dl = wid & 255;
    int base = b * RPB + dl;
    int p0 = rowp[base], p1 = rowp[base + 1];
    float acc = 0.f;
    int p = p0 + j;
    while (p < p1) {
        int s0 = __builtin_nontemporal_load(srt + p);
        int s1 = __builtin_nontemporal_load(srt + p + 8);
        int s2 = __builtin_nontemporal_load(srt + p + 16);
        int s3 = __builtin_nontemporal_load(srt + p + 24);
        int s4 = __builtin_nontemporal_load(srt + p + 32);
        int s5 = __builtin_nontemporal_load(srt + p + 40);
        int s6 = __builtin_nontemporal_load(srt + p + 48);
        int s7 = __builtin_nontemporal_load(srt + p + 56);
        s1 = (p + 8  < p1) ? s1 : N;
        s2 = (p + 16 < p1) ? s2 : N;
        s3 = (p + 24 < p1) ? s3 : N;
        s4 = (p + 32 < p1) ? s4 : N;
        s5 = (p + 40 < p1) ? s5 : N;
        s6 = (p + 48 < p1) ? s6 : N;
        s7 = (p + 56 < p1) ? s7 : N;
        float v0 = sx8[(size_t)s0 * 8 + k];
        float v1 = sx8[(size_t)s1 * 8 + k];
        float v2 = sx8[(size_t)s2 * 8 + k];
        float v3 = sx8[(size_t)s3 * 8 + k];
        float v4 = sx8[(size_t)s4 * 8 + k];
        float v5 = sx8[(size_t)s5 * 8 + k];
        float v6 = sx8[(size_t)s6 * 8 + k];
        float v7 = sx8[(size_t)s7 * 8 + k];
        acc += ((v0 + v1) + (v2 + v3)) + ((v4 + v5) + (v6 + v7));
        p += 64;
    }
    acc += __shfl_xor(acc, 8, 64);
    acc += __shfl_xor(acc, 16, 64);
    acc += __shfl_xor(acc, 32, 64);
    if (lane < 8) agg8[(size_t)wid * 8 + k] = acc + sx8[(size_t)wid * 8 + k];
}

// h1 = relu(dinv*(agg8[:5]@W1) + b1); g = dinv*h1 (16), stored fp16.
// thread i==N writes the zero row (tail target for gather16).
__global__ void k_lin1(const float* __restrict__ agg8, const float* __restrict__ dinv,
                       const float* __restrict__ W1, const float* __restrict__ b1,
                       __half* __restrict__ g, int N) {
    __shared__ float sW[80], sb[16];
    if (threadIdx.x < 80) sW[threadIdx.x] = W1[threadIdx.x];
    if (threadIdx.x < 16) sb[threadIdx.x] = b1[threadIdx.x];
    __syncthreads();
    int i = blockIdx.x * blockDim.x + threadIdx.x;
    if (i > N) return;
    uint4* gp = (uint4*)(g + (size_t)i * 16);   // 32B row
    if (i == N) {
        uint4 z = {0u, 0u, 0u, 0u};
        gp[0] = z; gp[1] = z;
        return;
    }
    float di = dinv[i];
    const float4* a4 = (const float4*)(agg8 + (size_t)i * 8);
    float4 v0 = a4[0], v1 = a4[1];
    float a[5] = {v0.x, v0.y, v0.z, v0.w, v1.x};
    union { __half h[16]; uint4 u[2]; } pk;
#pragma unroll
    for (int kk = 0; kk < 16; ++kk) {
        float h = 0.f;
#pragma unroll
        for (int d = 0; d < 5; ++d) h = fmaf(a[d], sW[d * 16 + kk], h);
        h = fmaxf(fmaf(di, h, sb[kk]), 0.f);
        pk.h[kk] = __float2half(h * di);
    }
    gp[0] = pk.u[0];
    gp[1] = pk.u[1];
}

// one wave per node; lane k in [0,8) owns feature PAIR (2k, 2k+1) via one
// packed __half2 load per slot (8 g-loads/round); 8 slots x depth 8; tail
// slots clamp to zeroed row N -> unconditional accumulate.
__global__ void k_gather16(const int* __restrict__ rowp, const int* __restrict__ srt,
                           const __half* __restrict__ g, float* __restrict__ agg16, int N) {
    int wid = (blockIdx.x * blockDim.x + threadIdx.x) >> 6;
    int lane = threadIdx.x & 63;
    if (wid >= N) return;
    int k = lane & 7, j = lane >> 3;
    int b = wid >> 8, dl = wid & 255;
    int base = b * RPB + dl;
    int p0 = rowp[base], p1 = rowp[base + 1];
    const __half2* gp = (const __half2*)g;      // row = 8 half2s
    float ax = 0.f, ay = 0.f;
    int p = p0 + j;
    while (p < p1) {
        int s0 = __builtin_nontemporal_load(srt + p);
        int s1 = __builtin_nontemporal_load(srt + p + 8);
        int s2 = __builtin_nontemporal_load(srt + p + 16);
        int s3 = __builtin_nontemporal_load(srt + p + 24);
        int s4 = __builtin_nontemporal_load(srt + p + 32);
        int s5 = __builtin_nontemporal_load(srt + p + 40);
        int s6 = __builtin_nontemporal_load(srt + p + 48);
        int s7 = __builtin_nontemporal_load(srt + p + 56);
        s1 = (p + 8  < p1) ? s1 : N;
        s2 = (p + 16 < p1) ? s2 : N;
        s3 = (p + 24 < p1) ? s3 : N;
        s4 = (p + 32 < p1) ? s4 : N;
        s5 = (p + 40 < p1) ? s5 : N;
        s6 = (p + 48 < p1) ? s6 : N;
        s7 = (p + 56 < p1) ? s7 : N;
        __half2 h0 = gp[(size_t)s0 * 8 + k];
        __half2 h1 = gp[(size_t)s1 * 8 + k];
        __half2 h2 = gp[(size_t)s2 * 8 + k];
        __half2 h3 = gp[(size_t)s3 * 8 + k];
        __half2 h4 = gp[(size_t)s4 * 8 + k];
        __half2 h5 = gp[(size_t)s5 * 8 + k];
        __half2 h6 = gp[(size_t)s6 * 8 + k];
        __half2 h7 = gp[(size_t)s7 * 8 + k];
        float2 f0 = __half22float2(h0);
        float2 f1 = __half22float2(h1);
        float2 f2 = __half22float2(h2);
        float2 f3 = __half22float2(h3);
        float2 f4 = __half22float2(h4);
        float2 f5 = __half22float2(h5);
        float2 f6 = __half22float2(h6);
        float2 f7 = __half22float2(h7);
        ax += ((f0.x + f1.x) + (f2.x + f3.x)) + ((f4.x + f5.x) + (f6.x + f7.x));
        ay += ((f0.y + f1.y) + (f2.y + f3.y)) + ((f4.y + f5.y) + (f6.y + f7.y));
        p += 64;
    }
    ax += __shfl_xor(ax, 8, 64);
    ax += __shfl_xor(ax, 16, 64);
    ax += __shfl_xor(ax, 32, 64);
    ay += __shfl_xor(ay, 8, 64);
    ay += __shfl_xor(ay, 16, 64);
    ay += __shfl_xor(ay, 32, 64);
    if (lane < 8) {
        float2 self = __half22float2(gp[(size_t)wid * 8 + k]);   // self-loop
        agg16[(size_t)wid * 16 + 2 * k]     = ax + self.x;
        agg16[(size_t)wid * 16 + 2 * k + 1] = ay + self.y;
    }
}

// h2 = relu(dinv*(agg16@W2) + b2); c = h2 . fcW; spread-8 pool atomics
__global__ void k_fin(const float* __restrict__ agg16, const float* __restrict__ dinv,
                      const float* __restrict__ W2, const float* __restrict__ b2,
                      const float* __restrict__ fcW, const int* __restrict__ batch,
                      float* __restrict__ pool, int* __restrict__ gcnt, int N, int G) {
    __shared__ float sW[512], sb[32], sf[32];
    for (int t = threadIdx.x; t < 512; t += blockDim.x) sW[t] = W2[t];
    if (threadIdx.x < 32) {
        sb[threadIdx.x] = b2[threadIdx.x];
        sf[threadIdx.x] = fcW[threadIdx.x];
    }
    __syncthreads();
    int i = blockIdx.x * blockDim.x + threadIdx.x;
    if (i >= N) return;
    float di = dinv[i];
    float a[16];
    const float4* a4 = (const float4*)(agg16 + (size_t)i * 16);
#pragma unroll
    for (int q = 0; q < 4; ++q) {
        float4 v = a4[q];
        a[q * 4 + 0] = v.x; a[q * 4 + 1] = v.y; a[q * 4 + 2] = v.z; a[q * 4 + 3] = v.w;
    }
    float c = 0.f;
#pragma unroll
    for (int jj = 0; jj < 32; ++jj) {
        float acc2 = 0.f;
#pragma unroll
        for (int kk = 0; kk < 16; ++kk) acc2 = fmaf(a[kk], sW[kk * 32 + jj], acc2);
        float h = fmaxf(fmaf(di, acc2, sb[jj]), 0.f);
        c = fmaf(h, sf[jj], c);
    }
    int bidx = batch[i];
    int slot = i & (PSPREAD - 1);
    atomicAdd(&pool[slot * G + bidx], c);
    atomicAdd(&gcnt[slot * G + bidx], 1);
}

__global__ void k_out(const float* __restrict__ pool, const int* __restrict__ gcnt,
                      const float* __restrict__ fcb, float* __restrict__ out, int G) {
    int gI = blockIdx.x * blockDim.x + threadIdx.x;
    if (gI >= G) return;
    float s = 0.f; int c = 0;
#pragma unroll
    for (int k = 0; k < PSPREAD; ++k) { s += pool[k * G + gI]; c += gcnt[k * G + gI]; }
    out[gI] = s / fmaxf((float)c, 1.f) + fcb[0];
}

extern "C" void kernel_launch(void* const* d_in, const int* in_sizes, int n_in,
                              void* d_out, int out_size, void* d_ws, size_t ws_size,
                              hipStream_t stream) {
    const float* x    = (const float*)d_in[0];
    const int*   ei   = (const int*)d_in[1];
    const int*   batch= (const int*)d_in[2];
    const float* W1   = (const float*)d_in[3];
    const float* b1   = (const float*)d_in[4];
    const float* W2   = (const float*)d_in[5];
    const float* b2   = (const float*)d_in[6];
    const float* fcW  = (const float*)d_in[7];
    const float* fcb  = (const float*)d_in[8];
    float* out = (float*)d_out;

    const int N = in_sizes[0] / 5;
    const int E = in_sizes[1] / 2;
    const int G = out_size;  // 1024
    const int chunk = (E + NBLK - 1) / NBLK;  // 6250 <= CHUNKMAX

    const int* src = ei;
    const int* dst = ei + E;

    // workspace carve, every buffer 256B-aligned
    char* ws = (char*)d_ws;
    size_t o = 0;
    auto carve = [&](size_t bytes) -> char* {
        char* p = ws + o;
        o += (bytes + 255) & ~(size_t)255;
        return p;
    };
    int*   bfill   = (int*)carve((size_t)4 * NB);
    int*   rowp    = (int*)carve((size_t)4 * (NB * RPB + 4));
    float* dinv    = (float*)carve((size_t)4 * N);
    float* sx8     = (float*)carve((size_t)32 * (N + 1));        // +1 zero row (gather8 tails)
    float* agg8    = (float*)carve((size_t)32 * N);              // 3.2 MB
    int*   srt     = (int*)carve((size_t)4 * NB * CAP + 256);    // 16 MB + pad
    char*  rbase   = carve((size_t)4 * NB * CAP);                // 16 MB
    // blkcnt/base alias srt (dead before k_sort writes srt)
    int*   blkcnt  = srt;                                        // [NBLK][NB]
    int*   base    = srt + (size_t)NBLK * NB;                    // [NB][NBLK]
    unsigned int* recbuf = (unsigned int*)rbase;                 // dead after k_sort
    __half* g      = (__half*)rbase;                             // (N+1) x 16 halves, post-k_sort
    float* agg16   = (float*)(rbase + (((size_t)32 * (N + 1) + 255) & ~(size_t)255)); // N x 16 f32
    float* pool    = (float*)carve((size_t)4 * PSPREAD * G);
    int*   gcnt    = (int*)carve((size_t)4 * PSPREAD * G);       // contiguous with pool

    hipMemsetAsync(pool, 0, (size_t)8 * PSPREAD * G, stream);    // pool + gcnt
    hipMemsetAsync(sx8 + (size_t)8 * N, 0, 32, stream);          // sx8 zero row

    k_cnt<<<NBLK, 256, 0, stream>>>(dst, E, chunk, blkcnt);
    k_scanb<<<NB, 512, 0, stream>>>(blkcnt, base, bfill);
    k_scat<<<NBLK, 512, 0, stream>>>(src, dst, E, chunk, base, recbuf);
    k_sort<<<NB, 512, 0, stream>>>(bfill, recbuf, rowp, srt, x, dinv, sx8, N);
    {
        int blocks = (int)(((long long)N * 64 + 255) / 256);
        k_gather8<<<blocks, 256, 0, stream>>>(rowp, srt, sx8, agg8, N);
    }
    k_lin1<<<(N + 256) / 256, 256, 0, stream>>>(agg8, dinv, W1, b1, g, N);
    {
        int blocks = (int)(((long long)N * 64 + 255) / 256);
        k_gather16<<<blocks, 256, 0, stream>>>(rowp, srt, g, agg16, N);
    }
    k_fin<<<(N + 255) / 256, 256, 0, stream>>>(agg16, dinv, W2, b2, fcW, batch, pool, gcnt, N, G);
    k_out<<<(G + 255) / 256, 256, 0, stream>>>(pool, gcnt, fcb, out, G);
}

// Round 21
// 156.079 us; speedup vs baseline: 1.2824x; 1.0687x over previous
//
#include <hip/hip_runtime.h>
#include <hip/hip_fp16.h>

// GCN: 2x GCNConv (5->16->32) + global mean pool + linear head.
// v20: v19 + (a) ALL hipMemsetAsync eliminated -- profile showed 42us
// fillBufferAligned dispatches for even 32B fills; pool/gcnt now zeroed by a
// grid-stride store in k_cnt, sx8's zero row written in k_sort, g's zero row
// already written by k_lin1; (b) sx8 table stored fp16 pair-packed (1.6 MB),
// gather8 uses half2 loads with k2=lane&3 x 16 slots x depth 4 (half the
// VMEM/addressing instructions of v19's scalar-f32 version).

#define RANGE 256          // nodes per bucket (d>>8)
#define NB 391             // ceil(100000/256)
#define RPB (RANGE + 1)    // rowp entries per bucket (incl. end)
#define CAP 10240          // record capacity per bucket (exact fill ~8184+-90)
#define NBLK 512           // edge-pass blocks
#define CHUNKMAX 6400      // >= ceil(E/NBLK) = 6250
#define PSPREAD 8

// per-block LDS histogram of dst buckets -> blkcnt[blk][NB]; also zeroes
// pool/gcnt (grid-stride store, replaces hipMemsetAsync).
__global__ void k_cnt(const int* __restrict__ dst, int E, int chunk,
                      int* __restrict__ blkcnt, int* __restrict__ poolgc, int nz) {
    int z = blockIdx.x * blockDim.x + threadIdx.x;
    if (z < nz) poolgc[z] = 0;
    __shared__ int h[NB];
    for (int t = threadIdx.x; t < NB; t += blockDim.x) h[t] = 0;
    __syncthreads();
    int e0 = blockIdx.x * chunk;
    int e1 = min(e0 + chunk, E);
    for (int e = e0 + threadIdx.x; e < e1; e += blockDim.x)
        atomicAdd(&h[dst[e] >> 8], 1);
    __syncthreads();
    int* row = blkcnt + (size_t)blockIdx.x * NB;
    for (int t = threadIdx.x; t < NB; t += blockDim.x) row[t] = h[t];
}

// one block per bucket: exclusive scan over the NBLK per-block counts.
__global__ __launch_bounds__(512) void k_scanb(const int* __restrict__ blkcnt,
        int* __restrict__ base, int* __restrict__ bfill) {
    __shared__ int part[NBLK];
    int b = blockIdx.x, t = threadIdx.x;   // NBLK == 512 threads
    int v = blkcnt[(size_t)t * NB + b];    // column read, L2-cached
    part[t] = v;
    __syncthreads();
    for (int off = 1; off < NBLK; off <<= 1) {
        int u = (t >= off) ? part[t - off] : 0;
        __syncthreads();
        part[t] += u;
        __syncthreads();
    }
    base[(size_t)b * NBLK + t] = b * CAP + part[t] - v;  // coalesced row write
    if (t == NBLK - 1) bfill[b] = part[t];
}

// scatter records at exact offsets, via LDS staging sorted by bucket, then
// burst writes (consecutive lanes -> consecutive addresses per segment).
__global__ __launch_bounds__(512) void k_scat(const int* __restrict__ src,
        const int* __restrict__ dst, int E, int chunk,
        const int* __restrict__ base, unsigned int* __restrict__ recbuf) {
    __shared__ unsigned int lbuf[CHUNKMAX];
    __shared__ unsigned short bkt[CHUNKMAX];
    __shared__ int h[NB], lsc[NB], h2[NB], base_l[NB];
    __shared__ int sc[512];
    int t = threadIdx.x;
    if (t < NB) { h[t] = 0; h2[t] = 0; }
    __syncthreads();
    int e0 = blockIdx.x * chunk;
    int e1 = min(e0 + chunk, E);
    int len = e1 - e0;
    for (int e = e0 + t; e < e1; e += 512)
        atomicAdd(&h[__builtin_nontemporal_load(dst + e) >> 8], 1);
    __syncthreads();
    int v = (t < NB) ? h[t] : 0;
    sc[t] = v;
    __syncthreads();
    for (int off = 1; off < 512; off <<= 1) {
        int u = (t >= off) ? sc[t - off] : 0;
        __syncthreads();
        sc[t] += u;
        __syncthreads();
    }
    if (t < NB) {
        lsc[t] = sc[t] - v;
        base_l[t] = base[(size_t)t * NBLK + blockIdx.x];  // column read, L2-cached
    }
    __syncthreads();
    for (int e = e0 + t; e < e1; e += 512) {
        int d = __builtin_nontemporal_load(dst + e);
        int s = __builtin_nontemporal_load(src + e);
        int b = d >> 8;
        int r = atomicAdd(&h2[b], 1);
        int pos = lsc[b] + r;
        lbuf[pos] = ((unsigned)s << 8) | (unsigned)(d & 255);
        bkt[pos] = (unsigned short)b;
    }
    __syncthreads();
    for (int i = t; i < len; i += 512) {
        int b = bkt[i];
        recbuf[base_l[b] + (i - lsc[b])] = lbuf[i];  // burst per segment
    }
}

// per-bucket LDS counting sort by dst_local; cnt[] doubles as degree, so
// dinv and the fp16 pair-packed sx8 row are computed here too (fused prep).
// Block 0 thread 0 also writes sx8's zero row N (gather8 tail target).
__global__ __launch_bounds__(512) void k_sort(const int* __restrict__ bfill,
        const unsigned int* __restrict__ recbuf, int* __restrict__ rowp,
        int* __restrict__ srt, const float* __restrict__ x,
        float* __restrict__ dinv, __half* __restrict__ sx8, int N) {
    __shared__ int cnt[RANGE], lbase[RANGE], rank[RANGE], sc[RANGE];
    int b = blockIdx.x;
    int t = threadIdx.x;
    if (t < RANGE) { cnt[t] = 0; rank[t] = 0; }
    if (b == 0 && t == 0) {
        uint4 z = {0u, 0u, 0u, 0u};
        *(uint4*)(sx8 + (size_t)N * 8) = z;     // zero row N
    }
    __syncthreads();
    int len = bfill[b];
    int g0 = b * CAP;
    const unsigned* rb = recbuf + (size_t)g0;
    for (int r = t; r < len; r += 512)
        atomicAdd(&cnt[__builtin_nontemporal_load(rb + r) & 255], 1);
    __syncthreads();
    if (t < RANGE) sc[t] = cnt[t];
    __syncthreads();
    for (int off = 1; off < RANGE; off <<= 1) {
        int u = 0;
        if (t < RANGE && t >= off) u = sc[t - off];
        __syncthreads();
        if (t < RANGE) sc[t] += u;
        __syncthreads();
    }
    if (t < RANGE) {
        lbase[t] = sc[t] - cnt[t];
        rowp[b * RPB + t] = g0 + lbase[t];
        if (t == RANGE - 1) rowp[b * RPB + RANGE] = g0 + sc[t];
        int i = b * RANGE + t;
        if (i < N) {
            float di = rsqrtf((float)(cnt[t] + 1));
            dinv[i] = di;
            union { __half h[8]; uint4 u; } pk;
#pragma unroll
            for (int d = 0; d < 5; ++d) pk.h[d] = __float2half(x[i * 5 + d] * di);
            pk.h[5] = __float2half(0.f); pk.h[6] = __float2half(0.f); pk.h[7] = __float2half(0.f);
            *(uint4*)(sx8 + (size_t)i * 8) = pk.u;
        }
    }
    __syncthreads();
    for (int r = t; r < len; r += 512) {
        unsigned rec = __builtin_nontemporal_load(rb + r);
        int key = (int)(rec & 255);
        int pos = g0 + lbase[key] + atomicAdd(&rank[key], 1);
        srt[pos] = (int)(rec >> 8);   // plain store: L2-merged in bucket slice
    }
}

// one wave per node; lane k2 in [0,4) owns feature PAIR (2k2, 2k2+1) via one
// packed __half2 load per slot; 16 slots x depth 4 (64 edges per latency
// round); tail slots clamp to zeroed row N -> unconditional accumulate.
__global__ void k_gather8(const int* __restrict__ rowp, const int* __restrict__ srt,
                          const __half* __restrict__ sx8, float* __restrict__ agg8, int N) {
    int wid = (blockIdx.x * blockDim.x + threadIdx.x) >> 6;
    int lane = threadIdx.x & 63;
    if (wid >= N) return;
    int k2 = lane & 3, j = lane >> 2;
    int b = wid >> 8, dl = wid & 255;
    int base = b * RPB + dl;
    int p0 = rowp[base], p1 = rowp[base + 1];
    const __half2* tab = (const __half2*)sx8;   // row = 4 half2s
    float ax = 0.f, ay = 0.f;
    int p = p0 + j;
    while (p < p1) {
        int s0 = __builtin_nontemporal_load(srt + p);
        int s1 = __builtin_nontemporal_load(srt + p + 16);
        int s2 = __builtin_nontemporal_load(srt + p + 32);
        int s3 = __builtin_nontemporal_load(srt + p + 48);
        s1 = (p + 16 < p1) ? s1 : N;
        s2 = (p + 32 < p1) ? s2 : N;
        s3 = (p + 48 < p1) ? s3 : N;
        __half2 h0 = tab[(size_t)s0 * 4 + k2];
        __half2 h1 = tab[(size_t)s1 * 4 + k2];
        __half2 h2 = tab[(size_t)s2 * 4 + k2];
        __half2 h3 = tab[(size_t)s3 * 4 + k2];
        float2 f0 = __half22float2(h0);
        float2 f1 = __half22float2(h1);
        float2 f2 = __half22float2(h2);
        float2 f3 = __half22float2(h3);
        ax += (f0.x + f1.x) + (f2.x + f3.x);
        ay += (f0.y + f1.y) + (f2.y + f3.y);
        p += 64;
    }
    ax += __shfl_xor(ax, 4, 64);
    ax += __shfl_xor(ax, 8, 64);
    ax += __shfl_xor(ax, 16, 64);
    ax += __shfl_xor(ax, 32, 64);
    ay += __shfl_xor(ay, 4, 64);
    ay += __shfl_xor(ay, 8, 64);
    ay += __shfl_xor(ay, 16, 64);
    ay += __shfl_xor(ay, 32, 64);
    if (lane < 4) {
        float2 self = __half22float2(tab[(size_t)wid * 4 + k2]);   // self-loop
        agg8[(size_t)wid * 8 + 2 * k2]     = ax + self.x;
        agg8[(size_t)wid * 8 + 2 * k2 + 1] = ay + self.y;
    }
}

// h1 = relu(dinv*(agg8[:5]@W1) + b1); g = dinv*h1 (16), stored fp16.
// thread i==N writes the zero row (tail target for gather16).
__global__ void k_lin1(const float* __restrict__ agg8, const float* __restrict__ dinv,
                       const float* __restrict__ W1, const float* __restrict__ b1,
                       __half* __restrict__ g, int N) {
    __shared__ float sW[80], sb[16];
    if (threadIdx.x < 80) sW[threadIdx.x] = W1[threadIdx.x];
    if (threadIdx.x < 16) sb[threadIdx.x] = b1[threadIdx.x];
    __syncthreads();
    int i = blockIdx.x * blockDim.x + threadIdx.x;
    if (i > N) return;
    uint4* gp = (uint4*)(g + (size_t)i * 16);   // 32B row
    if (i == N) {
        uint4 z = {0u, 0u, 0u, 0u};
        gp[0] = z; gp[1] = z;
        return;
    }
    float di = dinv[i];
    const float4* a4 = (const float4*)(agg8 + (size_t)i * 8);
    float4 v0 = a4[0], v1 = a4[1];
    float a[5] = {v0.x, v0.y, v0.z, v0.w, v1.x};
    union { __half h[16]; uint4 u[2]; } pk;
#pragma unroll
    for (int kk = 0; kk < 16; ++kk) {
        float h = 0.f;
#pragma unroll
        for (int d = 0; d < 5; ++d) h = fmaf(a[d], sW[d * 16 + kk], h);
        h = fmaxf(fmaf(di, h, sb[kk]), 0.f);
        pk.h[kk] = __float2half(h * di);
    }
    gp[0] = pk.u[0];
    gp[1] = pk.u[1];
}

// one wave per node; lane k in [0,8) owns feature PAIR (2k, 2k+1) via one
// packed __half2 load per slot (8 g-loads/round); 8 slots x depth 8; tail
// slots clamp to zeroed row N -> unconditional accumulate.
__global__ void k_gather16(const int* __restrict__ rowp, const int* __restrict__ srt,
                           const __half* __restrict__ g, float* __restrict__ agg16, int N) {
    int wid = (blockIdx.x * blockDim.x + threadIdx.x) >> 6;
    int lane = threadIdx.x & 63;
    if (wid >= N) return;
    int k = lane & 7, j = lane >> 3;
    int b = wid >> 8, dl = wid & 255;
    int base = b * RPB + dl;
    int p0 = rowp[base], p1 = rowp[base + 1];
    const __half2* gp = (const __half2*)g;      // row = 8 half2s
    float ax = 0.f, ay = 0.f;
    int p = p0 + j;
    while (p < p1) {
        int s0 = __builtin_nontemporal_load(srt + p);
        int s1 = __builtin_nontemporal_load(srt + p + 8);
        int s2 = __builtin_nontemporal_load(srt + p + 16);
        int s3 = __builtin_nontemporal_load(srt + p + 24);
        int s4 = __builtin_nontemporal_load(srt + p + 32);
        int s5 = __builtin_nontemporal_load(srt + p + 40);
        int s6 = __builtin_nontemporal_load(srt + p + 48);
        int s7 = __builtin_nontemporal_load(srt + p + 56);
        s1 = (p + 8  < p1) ? s1 : N;
        s2 = (p + 16 < p1) ? s2 : N;
        s3 = (p + 24 < p1) ? s3 : N;
        s4 = (p + 32 < p1) ? s4 : N;
        s5 = (p + 40 < p1) ? s5 : N;
        s6 = (p + 48 < p1) ? s6 : N;
        s7 = (p + 56 < p1) ? s7 : N;
        __half2 h0 = gp[(size_t)s0 * 8 + k];
        __half2 h1 = gp[(size_t)s1 * 8 + k];
        __half2 h2 = gp[(size_t)s2 * 8 + k];
        __half2 h3 = gp[(size_t)s3 * 8 + k];
        __half2 h4 = gp[(size_t)s4 * 8 + k];
        __half2 h5 = gp[(size_t)s5 * 8 + k];
        __half2 h6 = gp[(size_t)s6 * 8 + k];
        __half2 h7 = gp[(size_t)s7 * 8 + k];
        float2 f0 = __half22float2(h0);
        float2 f1 = __half22float2(h1);
        float2 f2 = __half22float2(h2);
        float2 f3 = __half22float2(h3);
        float2 f4 = __half22float2(h4);
        float2 f5 = __half22float2(h5);
        float2 f6 = __half22float2(h6);
        float2 f7 = __half22float2(h7);
        ax += ((f0.x + f1.x) + (f2.x + f3.x)) + ((f4.x + f5.x) + (f6.x + f7.x));
        ay += ((f0.y + f1.y) + (f2.y + f3.y)) + ((f4.y + f5.y) + (f6.y + f7.y));
        p += 64;
    }
    ax += __shfl_xor(ax, 8, 64);
    ax += __shfl_xor(ax, 16, 64);
    ax += __shfl_xor(ax, 32, 64);
    ay += __shfl_xor(ay, 8, 64);
    ay += __shfl_xor(ay, 16, 64);
    ay += __shfl_xor(ay, 32, 64);
    if (lane < 8) {
        float2 self = __half22float2(gp[(size_t)wid * 8 + k]);   // self-loop
        agg16[(size_t)wid * 16 + 2 * k]     = ax + self.x;
        agg16[(size_t)wid * 16 + 2 * k + 1] = ay + self.y;
    }
}

// h2 = relu(dinv*(agg16@W2) + b2); c = h2 . fcW; spread-8 pool atomics
__global__ void k_fin(const float* __restrict__ agg16, const float* __restrict__ dinv,
                      const float* __restrict__ W2, const float* __restrict__ b2,
                      const float* __restrict__ fcW, const int* __restrict__ batch,
                      float* __restrict__ pool, int* __restrict__ gcnt, int N, int G) {
    __shared__ float sW[512], sb[32], sf[32];
    for (int t = threadIdx.x; t < 512; t += blockDim.x) sW[t] = W2[t];
    if (threadIdx.x < 32) {
        sb[threadIdx.x] = b2[threadIdx.x];
        sf[threadIdx.x] = fcW[threadIdx.x];
    }
    __syncthreads();
    int i = blockIdx.x * blockDim.x + threadIdx.x;
    if (i >= N) return;
    float di = dinv[i];
    float a[16];
    const float4* a4 = (const float4*)(agg16 + (size_t)i * 16);
#pragma unroll
    for (int q = 0; q < 4; ++q) {
        float4 v = a4[q];
        a[q * 4 + 0] = v.x; a[q * 4 + 1] = v.y; a[q * 4 + 2] = v.z; a[q * 4 + 3] = v.w;
    }
    float c = 0.f;
#pragma unroll
    for (int jj = 0; jj < 32; ++jj) {
        float acc2 = 0.f;
#pragma unroll
        for (int kk = 0; kk < 16; ++kk) acc2 = fmaf(a[kk], sW[kk * 32 + jj], acc2);
        float h = fmaxf(fmaf(di, acc2, sb[jj]), 0.f);
        c = fmaf(h, sf[jj], c);
    }
    int bidx = batch[i];
    int slot = i & (PSPREAD - 1);
    atomicAdd(&pool[slot * G + bidx], c);
    atomicAdd(&gcnt[slot * G + bidx], 1);
}

__global__ void k_out(const float* __restrict__ pool, const int* __restrict__ gcnt,
                      const float* __restrict__ fcb, float* __restrict__ out, int G) {
    int gI = blockIdx.x * blockDim.x + threadIdx.x;
    if (gI >= G) return;
    float s = 0.f; int c = 0;
#pragma unroll
    for (int k = 0; k < PSPREAD; ++k) { s += pool[k * G + gI]; c += gcnt[k * G + gI]; }
    out[gI] = s / fmaxf((float)c, 1.f) + fcb[0];
}

extern "C" void kernel_launch(void* const* d_in, const int* in_sizes, int n_in,
                              void* d_out, int out_size, void* d_ws, size_t ws_size,
                              hipStream_t stream) {
    const float* x    = (const float*)d_in[0];
    const int*   ei   = (const int*)d_in[1];
    const int*   batch= (const int*)d_in[2];
    const float* W1   = (const float*)d_in[3];
    const float* b1   = (const float*)d_in[4];
    const float* W2   = (const float*)d_in[5];
    const float* b2   = (const float*)d_in[6];
    const float* fcW  = (const float*)d_in[7];
    const float* fcb  = (const float*)d_in[8];
    float* out = (float*)d_out;

    const int N = in_sizes[0] / 5;
    const int E = in_sizes[1] / 2;
    const int G = out_size;  // 1024
    const int chunk = (E + NBLK - 1) / NBLK;  // 6250 <= CHUNKMAX

    const int* src = ei;
    const int* dst = ei + E;

    // workspace carve, every buffer 256B-aligned
    char* ws = (char*)d_ws;
    size_t o = 0;
    auto carve = [&](size_t bytes) -> char* {
        char* p = ws + o;
        o += (bytes + 255) & ~(size_t)255;
        return p;
    };
    int*    bfill   = (int*)carve((size_t)4 * NB);
    int*    rowp    = (int*)carve((size_t)4 * (NB * RPB + 4));
    float*  dinv    = (float*)carve((size_t)4 * N);
    __half* sx8     = (__half*)carve((size_t)16 * (N + 1));      // fp16 rows + zero row
    float*  agg8    = (float*)carve((size_t)32 * N);             // 3.2 MB
    int*    srt     = (int*)carve((size_t)4 * NB * CAP + 256);   // 16 MB + pad
    char*   rbase   = carve((size_t)4 * NB * CAP);               // 16 MB
    // blkcnt/base alias srt (dead before k_sort writes srt)
    int*    blkcnt  = srt;                                       // [NBLK][NB]
    int*    base    = srt + (size_t)NBLK * NB;                   // [NB][NBLK]
    unsigned int* recbuf = (unsigned int*)rbase;                 // dead after k_sort
    __half* g       = (__half*)rbase;                            // (N+1) x 16 halves, post-k_sort
    float*  agg16   = (float*)(rbase + (((size_t)32 * (N + 1) + 255) & ~(size_t)255)); // N x 16 f32
    float*  pool    = (float*)carve((size_t)4 * PSPREAD * G);
    int*    gcnt    = (int*)carve((size_t)4 * PSPREAD * G);      // contiguous with pool

    const int nz = 2 * PSPREAD * G;   // pool + gcnt ints, zeroed in k_cnt

    k_cnt<<<NBLK, 256, 0, stream>>>(dst, E, chunk, blkcnt, (int*)pool, nz);
    k_scanb<<<NB, 512, 0, stream>>>(blkcnt, base, bfill);
    k_scat<<<NBLK, 512, 0, stream>>>(src, dst, E, chunk, base, recbuf);
    k_sort<<<NB, 512, 0, stream>>>(bfill, recbuf, rowp, srt, x, dinv, sx8, N);
    {
        int blocks = (int)(((long long)N * 64 + 255) / 256);
        k_gather8<<<blocks, 256, 0, stream>>>(rowp, srt, sx8, agg8, N);
    }
    k_lin1<<<(N + 256) / 256, 256, 0, stream>>>(agg8, dinv, W1, b1, g, N);
    {
        int blocks = (int)(((long long)N * 64 + 255) / 256);
        k_gather16<<<blocks, 256, 0, stream>>>(rowp, srt, g, agg16, N);
    }
    k_fin<<<(N + 255) / 256, 256, 0, stream>>>(agg16, dinv, W2, b2, fcW, batch, pool, gcnt, N, G);
    k_out<<<(G + 255) / 256, 256, 0, stream>>>(pool, gcnt, fcb, out, G);
}

// Round 22
// 145.241 us; speedup vs baseline: 1.3781x; 1.0746x over previous
//
#include <hip/hip_runtime.h>
#include <hip/hip_fp16.h>

// GCN: 2x GCNConv (5->16->32) + global mean pool + linear head.
// v21: v20 + two-nodes-per-wave gathers (32 lanes per node). Each VMEM
// instruction in the gather loop now serves both nodes (lockstep halves),
// halving per-node instruction count for deg<=32 (the bulk of Poisson(32))
// and halving wave count -> per-node prologue/epilogue cost. Reduction is
// xor 8,16 within each 32-lane half. Build pipeline identical to v20.

#define RANGE 256          // nodes per bucket (d>>8)
#define NB 391             // ceil(100000/256)
#define RPB (RANGE + 1)    // rowp entries per bucket (incl. end)
#define CAP 10240          // record capacity per bucket (exact fill ~8184+-90)
#define NBLK 512           // edge-pass blocks
#define CHUNKMAX 6400      // >= ceil(E/NBLK) = 6250
#define PSPREAD 8

// per-block LDS histogram of dst buckets -> blkcnt[blk][NB]; also zeroes
// pool/gcnt (grid-stride store, replaces hipMemsetAsync).
__global__ void k_cnt(const int* __restrict__ dst, int E, int chunk,
                      int* __restrict__ blkcnt, int* __restrict__ poolgc, int nz) {
    int z = blockIdx.x * blockDim.x + threadIdx.x;
    if (z < nz) poolgc[z] = 0;
    __shared__ int h[NB];
    for (int t = threadIdx.x; t < NB; t += blockDim.x) h[t] = 0;
    __syncthreads();
    int e0 = blockIdx.x * chunk;
    int e1 = min(e0 + chunk, E);
    for (int e = e0 + threadIdx.x; e < e1; e += blockDim.x)
        atomicAdd(&h[dst[e] >> 8], 1);
    __syncthreads();
    int* row = blkcnt + (size_t)blockIdx.x * NB;
    for (int t = threadIdx.x; t < NB; t += blockDim.x) row[t] = h[t];
}

// one block per bucket: exclusive scan over the NBLK per-block counts.
__global__ __launch_bounds__(512) void k_scanb(const int* __restrict__ blkcnt,
        int* __restrict__ base, int* __restrict__ bfill) {
    __shared__ int part[NBLK];
    int b = blockIdx.x, t = threadIdx.x;   // NBLK == 512 threads
    int v = blkcnt[(size_t)t * NB + b];    // column read, L2-cached
    part[t] = v;
    __syncthreads();
    for (int off = 1; off < NBLK; off <<= 1) {
        int u = (t >= off) ? part[t - off] : 0;
        __syncthreads();
        part[t] += u;
        __syncthreads();
    }
    base[(size_t)b * NBLK + t] = b * CAP + part[t] - v;  // coalesced row write
    if (t == NBLK - 1) bfill[b] = part[t];
}

// scatter records at exact offsets, via LDS staging sorted by bucket, then
// burst writes (consecutive lanes -> consecutive addresses per segment).
__global__ __launch_bounds__(512) void k_scat(const int* __restrict__ src,
        const int* __restrict__ dst, int E, int chunk,
        const int* __restrict__ base, unsigned int* __restrict__ recbuf) {
    __shared__ unsigned int lbuf[CHUNKMAX];
    __shared__ unsigned short bkt[CHUNKMAX];
    __shared__ int h[NB], lsc[NB], h2[NB], base_l[NB];
    __shared__ int sc[512];
    int t = threadIdx.x;
    if (t < NB) { h[t] = 0; h2[t] = 0; }
    __syncthreads();
    int e0 = blockIdx.x * chunk;
    int e1 = min(e0 + chunk, E);
    int len = e1 - e0;
    for (int e = e0 + t; e < e1; e += 512)
        atomicAdd(&h[__builtin_nontemporal_load(dst + e) >> 8], 1);
    __syncthreads();
    int v = (t < NB) ? h[t] : 0;
    sc[t] = v;
    __syncthreads();
    for (int off = 1; off < 512; off <<= 1) {
        int u = (t >= off) ? sc[t - off] : 0;
        __syncthreads();
        sc[t] += u;
        __syncthreads();
    }
    if (t < NB) {
        lsc[t] = sc[t] - v;
        base_l[t] = base[(size_t)t * NBLK + blockIdx.x];  // column read, L2-cached
    }
    __syncthreads();
    for (int e = e0 + t; e < e1; e += 512) {
        int d = __builtin_nontemporal_load(dst + e);
        int s = __builtin_nontemporal_load(src + e);
        int b = d >> 8;
        int r = atomicAdd(&h2[b], 1);
        int pos = lsc[b] + r;
        lbuf[pos] = ((unsigned)s << 8) | (unsigned)(d & 255);
        bkt[pos] = (unsigned short)b;
    }
    __syncthreads();
    for (int i = t; i < len; i += 512) {
        int b = bkt[i];
        recbuf[base_l[b] + (i - lsc[b])] = lbuf[i];  // burst per segment
    }
}

// per-bucket LDS counting sort by dst_local; cnt[] doubles as degree, so
// dinv and the fp16 pair-packed sx8 row are computed here too (fused prep).
// Block 0 thread 0 also writes sx8's zero row N (gather8 tail target).
__global__ __launch_bounds__(512) void k_sort(const int* __restrict__ bfill,
        const unsigned int* __restrict__ recbuf, int* __restrict__ rowp,
        int* __restrict__ srt, const float* __restrict__ x,
        float* __restrict__ dinv, __half* __restrict__ sx8, int N) {
    __shared__ int cnt[RANGE], lbase[RANGE], rank[RANGE], sc[RANGE];
    int b = blockIdx.x;
    int t = threadIdx.x;
    if (t < RANGE) { cnt[t] = 0; rank[t] = 0; }
    if (b == 0 && t == 0) {
        uint4 z = {0u, 0u, 0u, 0u};
        *(uint4*)(sx8 + (size_t)N * 8) = z;     // zero row N
    }
    __syncthreads();
    int len = bfill[b];
    int g0 = b * CAP;
    const unsigned* rb = recbuf + (size_t)g0;
    for (int r = t; r < len; r += 512)
        atomicAdd(&cnt[__builtin_nontemporal_load(rb + r) & 255], 1);
    __syncthreads();
    if (t < RANGE) sc[t] = cnt[t];
    __syncthreads();
    for (int off = 1; off < RANGE; off <<= 1) {
        int u = 0;
        if (t < RANGE && t >= off) u = sc[t - off];
        __syncthreads();
        if (t < RANGE) sc[t] += u;
        __syncthreads();
    }
    if (t < RANGE) {
        lbase[t] = sc[t] - cnt[t];
        rowp[b * RPB + t] = g0 + lbase[t];
        if (t == RANGE - 1) rowp[b * RPB + RANGE] = g0 + sc[t];
        int i = b * RANGE + t;
        if (i < N) {
            float di = rsqrtf((float)(cnt[t] + 1));
            dinv[i] = di;
            union { __half h[8]; uint4 u; } pk;
#pragma unroll
            for (int d = 0; d < 5; ++d) pk.h[d] = __float2half(x[i * 5 + d] * di);
            pk.h[5] = __float2half(0.f); pk.h[6] = __float2half(0.f); pk.h[7] = __float2half(0.f);
            *(uint4*)(sx8 + (size_t)i * 8) = pk.u;
        }
    }
    __syncthreads();
    for (int r = t; r < len; r += 512) {
        unsigned rec = __builtin_nontemporal_load(rb + r);
        int key = (int)(rec & 255);
        int pos = g0 + lbase[key] + atomicAdd(&rank[key], 1);
        srt[pos] = (int)(rec >> 8);   // plain store: L2-merged in bucket slice
    }
}

// TWO nodes per wave (32 lanes each). Per half: lane k2 in [0,4) owns feature
// pair (2k2,2k2+1); j in [0,8) slots; depth 4 -> 32 edges per round. Tail
// slots clamp to zeroed row N. Reduce: xor 4,8,16 (stays within the half).
__global__ void k_gather8(const int* __restrict__ rowp, const int* __restrict__ srt,
                          const __half* __restrict__ sx8, float* __restrict__ agg8, int N) {
    int wv = (blockIdx.x * blockDim.x + threadIdx.x) >> 6;
    int lane = threadIdx.x & 63;
    int hl = lane & 31;
    int node = wv * 2 + (lane >> 5);
    if (node >= N) return;
    int k2 = hl & 3, j = hl >> 2;
    int b = node >> 8, dl = node & 255;
    int base = b * RPB + dl;
    int p0 = rowp[base], p1 = rowp[base + 1];
    const __half2* tab = (const __half2*)sx8;   // row = 4 half2s
    float ax = 0.f, ay = 0.f;
    int p = p0 + j;
    while (p < p1) {
        int s0 = __builtin_nontemporal_load(srt + p);
        int s1 = __builtin_nontemporal_load(srt + p + 8);
        int s2 = __builtin_nontemporal_load(srt + p + 16);
        int s3 = __builtin_nontemporal_load(srt + p + 24);
        s1 = (p + 8  < p1) ? s1 : N;
        s2 = (p + 16 < p1) ? s2 : N;
        s3 = (p + 24 < p1) ? s3 : N;
        float2 f0 = __half22float2(tab[(size_t)s0 * 4 + k2]);
        float2 f1 = __half22float2(tab[(size_t)s1 * 4 + k2]);
        float2 f2 = __half22float2(tab[(size_t)s2 * 4 + k2]);
        float2 f3 = __half22float2(tab[(size_t)s3 * 4 + k2]);
        ax += (f0.x + f1.x) + (f2.x + f3.x);
        ay += (f0.y + f1.y) + (f2.y + f3.y);
        p += 32;
    }
    ax += __shfl_xor(ax, 4, 64);
    ax += __shfl_xor(ax, 8, 64);
    ax += __shfl_xor(ax, 16, 64);
    ay += __shfl_xor(ay, 4, 64);
    ay += __shfl_xor(ay, 8, 64);
    ay += __shfl_xor(ay, 16, 64);
    if (hl < 4) {
        float2 self = __half22float2(tab[(size_t)node * 4 + k2]);   // self-loop
        agg8[(size_t)node * 8 + 2 * k2]     = ax + self.x;
        agg8[(size_t)node * 8 + 2 * k2 + 1] = ay + self.y;
    }
}

// h1 = relu(dinv*(agg8[:5]@W1) + b1); g = dinv*h1 (16), stored fp16.
// thread i==N writes the zero row (tail target for gather16).
__global__ void k_lin1(const float* __restrict__ agg8, const float* __restrict__ dinv,
                       const float* __restrict__ W1, const float* __restrict__ b1,
                       __half* __restrict__ g, int N) {
    __shared__ float sW[80], sb[16];
    if (threadIdx.x < 80) sW[threadIdx.x] = W1[threadIdx.x];
    if (threadIdx.x < 16) sb[threadIdx.x] = b1[threadIdx.x];
    __syncthreads();
    int i = blockIdx.x * blockDim.x + threadIdx.x;
    if (i > N) return;
    uint4* gp = (uint4*)(g + (size_t)i * 16);   // 32B row
    if (i == N) {
        uint4 z = {0u, 0u, 0u, 0u};
        gp[0] = z; gp[1] = z;
        return;
    }
    float di = dinv[i];
    const float4* a4 = (const float4*)(agg8 + (size_t)i * 8);
    float4 v0 = a4[0], v1 = a4[1];
    float a[5] = {v0.x, v0.y, v0.z, v0.w, v1.x};
    union { __half h[16]; uint4 u[2]; } pk;
#pragma unroll
    for (int kk = 0; kk < 16; ++kk) {
        float h = 0.f;
#pragma unroll
        for (int d = 0; d < 5; ++d) h = fmaf(a[d], sW[d * 16 + kk], h);
        h = fmaxf(fmaf(di, h, sb[kk]), 0.f);
        pk.h[kk] = __float2half(h * di);
    }
    gp[0] = pk.u[0];
    gp[1] = pk.u[1];
}

// TWO nodes per wave (32 lanes each). Per half: lane k in [0,8) owns feature
// pair (2k,2k+1); j in [0,4) slots; depth 8 -> 32 edges per round. Tail slots
// clamp to zeroed row N. Reduce: xor 8,16 (stays within the half).
__global__ void k_gather16(const int* __restrict__ rowp, const int* __restrict__ srt,
                           const __half* __restrict__ g, float* __restrict__ agg16, int N) {
    int wv = (blockIdx.x * blockDim.x + threadIdx.x) >> 6;
    int lane = threadIdx.x & 63;
    int hl = lane & 31;
    int node = wv * 2 + (lane >> 5);
    if (node >= N) return;
    int k = hl & 7, j = hl >> 3;
    int b = node >> 8, dl = node & 255;
    int base = b * RPB + dl;
    int p0 = rowp[base], p1 = rowp[base + 1];
    const __half2* gp = (const __half2*)g;      // row = 8 half2s
    float ax = 0.f, ay = 0.f;
    int p = p0 + j;
    while (p < p1) {
        int s0 = __builtin_nontemporal_load(srt + p);
        int s1 = __builtin_nontemporal_load(srt + p + 4);
        int s2 = __builtin_nontemporal_load(srt + p + 8);
        int s3 = __builtin_nontemporal_load(srt + p + 12);
        int s4 = __builtin_nontemporal_load(srt + p + 16);
        int s5 = __builtin_nontemporal_load(srt + p + 20);
        int s6 = __builtin_nontemporal_load(srt + p + 24);
        int s7 = __builtin_nontemporal_load(srt + p + 28);
        s1 = (p + 4  < p1) ? s1 : N;
        s2 = (p + 8  < p1) ? s2 : N;
        s3 = (p + 12 < p1) ? s3 : N;
        s4 = (p + 16 < p1) ? s4 : N;
        s5 = (p + 20 < p1) ? s5 : N;
        s6 = (p + 24 < p1) ? s6 : N;
        s7 = (p + 28 < p1) ? s7 : N;
        float2 f0 = __half22float2(gp[(size_t)s0 * 8 + k]);
        float2 f1 = __half22float2(gp[(size_t)s1 * 8 + k]);
        float2 f2 = __half22float2(gp[(size_t)s2 * 8 + k]);
        float2 f3 = __half22float2(gp[(size_t)s3 * 8 + k]);
        float2 f4 = __half22float2(gp[(size_t)s4 * 8 + k]);
        float2 f5 = __half22float2(gp[(size_t)s5 * 8 + k]);
        float2 f6 = __half22float2(gp[(size_t)s6 * 8 + k]);
        float2 f7 = __half22float2(gp[(size_t)s7 * 8 + k]);
        ax += ((f0.x + f1.x) + (f2.x + f3.x)) + ((f4.x + f5.x) + (f6.x + f7.x));
        ay += ((f0.y + f1.y) + (f2.y + f3.y)) + ((f4.y + f5.y) + (f6.y + f7.y));
        p += 32;
    }
    ax += __shfl_xor(ax, 8, 64);
    ax += __shfl_xor(ax, 16, 64);
    ay += __shfl_xor(ay, 8, 64);
    ay += __shfl_xor(ay, 16, 64);
    if (hl < 8) {
        float2 self = __half22float2(gp[(size_t)node * 8 + k]);   // self-loop
        agg16[(size_t)node * 16 + 2 * k]     = ax + self.x;
        agg16[(size_t)node * 16 + 2 * k + 1] = ay + self.y;
    }
}

// h2 = relu(dinv*(agg16@W2) + b2); c = h2 . fcW; spread-8 pool atomics
__global__ void k_fin(const float* __restrict__ agg16, const float* __restrict__ dinv,
                      const float* __restrict__ W2, const float* __restrict__ b2,
                      const float* __restrict__ fcW, const int* __restrict__ batch,
                      float* __restrict__ pool, int* __restrict__ gcnt, int N, int G) {
    __shared__ float sW[512], sb[32], sf[32];
    for (int t = threadIdx.x; t < 512; t += blockDim.x) sW[t] = W2[t];
    if (threadIdx.x < 32) {
        sb[threadIdx.x] = b2[threadIdx.x];
        sf[threadIdx.x] = fcW[threadIdx.x];
    }
    __syncthreads();
    int i = blockIdx.x * blockDim.x + threadIdx.x;
    if (i >= N) return;
    float di = dinv[i];
    float a[16];
    const float4* a4 = (const float4*)(agg16 + (size_t)i * 16);
#pragma unroll
    for (int q = 0; q < 4; ++q) {
        float4 v = a4[q];
        a[q * 4 + 0] = v.x; a[q * 4 + 1] = v.y; a[q * 4 + 2] = v.z; a[q * 4 + 3] = v.w;
    }
    float c = 0.f;
#pragma unroll
    for (int jj = 0; jj < 32; ++jj) {
        float acc2 = 0.f;
#pragma unroll
        for (int kk = 0; kk < 16; ++kk) acc2 = fmaf(a[kk], sW[kk * 32 + jj], acc2);
        float h = fmaxf(fmaf(di, acc2, sb[jj]), 0.f);
        c = fmaf(h, sf[jj], c);
    }
    int bidx = batch[i];
    int slot = i & (PSPREAD - 1);
    atomicAdd(&pool[slot * G + bidx], c);
    atomicAdd(&gcnt[slot * G + bidx], 1);
}

__global__ void k_out(const float* __restrict__ pool, const int* __restrict__ gcnt,
                      const float* __restrict__ fcb, float* __restrict__ out, int G) {
    int gI = blockIdx.x * blockDim.x + threadIdx.x;
    if (gI >= G) return;
    float s = 0.f; int c = 0;
#pragma unroll
    for (int k = 0; k < PSPREAD; ++k) { s += pool[k * G + gI]; c += gcnt[k * G + gI]; }
    out[gI] = s / fmaxf((float)c, 1.f) + fcb[0];
}

extern "C" void kernel_launch(void* const* d_in, const int* in_sizes, int n_in,
                              void* d_out, int out_size, void* d_ws, size_t ws_size,
                              hipStream_t stream) {
    const float* x    = (const float*)d_in[0];
    const int*   ei   = (const int*)d_in[1];
    const int*   batch= (const int*)d_in[2];
    const float* W1   = (const float*)d_in[3];
    const float* b1   = (const float*)d_in[4];
    const float* W2   = (const float*)d_in[5];
    const float* b2   = (const float*)d_in[6];
    const float* fcW  = (const float*)d_in[7];
    const float* fcb  = (const float*)d_in[8];
    float* out = (float*)d_out;

    const int N = in_sizes[0] / 5;
    const int E = in_sizes[1] / 2;
    const int G = out_size;  // 1024
    const int chunk = (E + NBLK - 1) / NBLK;  // 6250 <= CHUNKMAX

    const int* src = ei;
    const int* dst = ei + E;

    // workspace carve, every buffer 256B-aligned
    char* ws = (char*)d_ws;
    size_t o = 0;
    auto carve = [&](size_t bytes) -> char* {
        char* p = ws + o;
        o += (bytes + 255) & ~(size_t)255;
        return p;
    };
    int*    bfill   = (int*)carve((size_t)4 * NB);
    int*    rowp    = (int*)carve((size_t)4 * (NB * RPB + 4));
    float*  dinv    = (float*)carve((size_t)4 * N);
    __half* sx8     = (__half*)carve((size_t)16 * (N + 1));      // fp16 rows + zero row
    float*  agg8    = (float*)carve((size_t)32 * N);             // 3.2 MB
    int*    srt     = (int*)carve((size_t)4 * NB * CAP + 256);   // 16 MB + pad
    char*   rbase   = carve((size_t)4 * NB * CAP);               // 16 MB
    // blkcnt/base alias srt (dead before k_sort writes srt)
    int*    blkcnt  = srt;                                       // [NBLK][NB]
    int*    base    = srt + (size_t)NBLK * NB;                   // [NB][NBLK]
    unsigned int* recbuf = (unsigned int*)rbase;                 // dead after k_sort
    __half* g       = (__half*)rbase;                            // (N+1) x 16 halves, post-k_sort
    float*  agg16   = (float*)(rbase + (((size_t)32 * (N + 1) + 255) & ~(size_t)255)); // N x 16 f32
    float*  pool    = (float*)carve((size_t)4 * PSPREAD * G);
    int*    gcnt    = (int*)carve((size_t)4 * PSPREAD * G);      // contiguous with pool

    const int nz = 2 * PSPREAD * G;   // pool + gcnt ints, zeroed in k_cnt

    k_cnt<<<NBLK, 256, 0, stream>>>(dst, E, chunk, blkcnt, (int*)pool, nz);
    k_scanb<<<NB, 512, 0, stream>>>(blkcnt, base, bfill);
    k_scat<<<NBLK, 512, 0, stream>>>(src, dst, E, chunk, base, recbuf);
    k_sort<<<NB, 512, 0, stream>>>(bfill, recbuf, rowp, srt, x, dinv, sx8, N);
    {
        long long waves = (N + 1) / 2;
        int blocks = (int)((waves * 64 + 255) / 256);
        k_gather8<<<blocks, 256, 0, stream>>>(rowp, srt, sx8, agg8, N);
    }
    k_lin1<<<(N + 256) / 256, 256, 0, stream>>>(agg8, dinv, W1, b1, g, N);
    {
        long long waves = (N + 1) / 2;
        int blocks = (int)((waves * 64 + 255) / 256);
        k_gather16<<<blocks, 256, 0, stream>>>(rowp, srt, g, agg16, N);
    }
    k_fin<<<(N + 255) / 256, 256, 0, stream>>>(agg16, dinv, W2, b2, fcW, batch, pool, gcnt, N, G);
    k_out<<<(G + 255) / 256, 256, 0, stream>>>(pool, gcnt, fcb, out, G);
}